// Round 8
// baseline (806.852 us; speedup 1.0000x reference)
//
#include <hip/hip_runtime.h>
#include <stdint.h>

typedef unsigned short u16;
typedef unsigned char u8;
typedef __attribute__((ext_vector_type(8))) short bf16x8;
typedef __attribute__((ext_vector_type(4))) float f32x4;

#define NU_C 30000
#define NI_C 10000
#define N_C  40000
#define E_C  100000
#define B_C  8192

static __device__ __forceinline__ float bf2f(u16 u) {
    union { unsigned int i; float f; } c; c.i = ((unsigned int)u) << 16; return c.f;
}
static __device__ __forceinline__ u16 f2bf(float f) {
    union { float f; unsigned int i; } c; c.f = f;
    return (u16)((c.i + 0x7FFFu + ((c.i >> 16) & 1u)) >> 16);
}
static __device__ __forceinline__ float wave_sum(float v) {
#pragma unroll
    for (int off = 32; off > 0; off >>= 1) v += __shfl_xor(v, off);
    return v;
}

__global__ void zero_kernel(unsigned int* p, int n) {
    int i = blockIdx.x * 256 + threadIdx.x;
    if (i < n) p[i] = 0u;
}
__global__ void fillval_kernel(float* p, int n, float v) {
    int i = blockIdx.x * 256 + threadIdx.x;
    if (i < n) p[i] = v;
}

// ---- bool-layout detection ----
__global__ void detect_kernel(const unsigned int* a, int n, int* flag) {
    int i = blockIdx.x * 256 + threadIdx.x;
    if (i >= n) return;
    unsigned int v = a[i];
    int f = 0;
    if (v > 1u) f |= 1;
    if (v != 0u && v != 0x3F800000u) f |= 2;
    if (f) atomicOr(flag, f);
}
__global__ void conv_mask_kernel(const void* raw, u8* outm, int n, const int* flag) {
    int i = blockIdx.x * 256 + threadIdx.x;
    if (i >= n) return;
    const int f = *flag;
    u8 r;
    if ((f & 1) == 0)      r = ((const int*)raw)[i] != 0;
    else if ((f & 2) == 0) r = ((const float*)raw)[i] != 0.f;
    else                   r = ((const u8*)raw)[i] != 0;
    outm[i] = r;
}

// ---- f32 -> bf16 conversion for the three embedding inputs ----
__global__ void conv3_kernel(const float* __restrict__ a, int na4,
                             const float* __restrict__ b, int nb4,
                             const float* __restrict__ c, int nc4,
                             u16* __restrict__ oa, u16* __restrict__ ob, u16* __restrict__ oc)
{
    int tot = na4 + nb4 + nc4;
    for (int i = blockIdx.x * 256 + threadIdx.x; i < tot; i += gridDim.x * 256) {
        const float* s; u16* o; int j = i;
        if (j < na4) { s = a; o = oa; }
        else if ((j -= na4) < nb4) { s = b; o = ob; }
        else { j -= nb4; s = c; o = oc; }
        float4 v = *(const float4*)&s[(size_t)j * 4];
        ushort4 r;
        r.x = f2bf(v.x); r.y = f2bf(v.y); r.z = f2bf(v.z); r.w = f2bf(v.w);
        *(ushort4*)&o[(size_t)j * 4] = r;
    }
}

// ---- batched weight transpose+convert: WT[n*K + k] = bf16(W[k*ldw + coloff + n]) ----
#define WT_ELEMS 1359872
__device__ const int wd_prefix[23] = {0,16384,32768,49152,114688,180224,245760,311296,442368,
    507904,573440,638976,704512,770048,835584,901120,966656,1032192,1097728,1163264,1228800,
    1294336,1359872};
__device__ const u8  wd_src[22]  = {0,1,2,3,4,5,6,7,8,9,10,11,12,10,11,12,10,11,12,10,11,12};
__device__ const short wd_ldw[22]= {256,256,256,256,256,256,256,256,256,256,
    1024,1024,1024,1024,1024,1024,1024,1024,1024,1024,1024,1024};
__device__ const short wd_coff[22]={0,0,0,0,0,0,0,0,0,0, 0,0,0, 256,256,256, 512,512,512, 768,768,768};
__device__ const short wd_kmask[22]={63,63,63,255,255,255,255,511,255,255,
    255,255,255,255,255,255,255,255,255,255,255,255};
__device__ const u8  wd_ksh[22] = {6,6,6,8,8,8,8,9,8,8, 8,8,8,8,8,8,8,8,8,8,8,8};

__global__ __launch_bounds__(256)
void wtrans_kernel(const float* w0, const float* w1, const float* w2, const float* w3,
                   const float* w4, const float* w5, const float* w6, const float* w7,
                   const float* w8, const float* w9, const float* w10, const float* w11,
                   const float* w12, u16* __restrict__ WT)
{
    int idx = blockIdx.x * 256 + threadIdx.x;
    if (idx >= WT_ELEMS) return;
    int d = 0;
    while (wd_prefix[d + 1] <= idx) ++d;
    const int local = idx - wd_prefix[d];
    const int k = local & wd_kmask[d];
    const int n = local >> wd_ksh[d];
    const float* s;
    switch (wd_src[d]) {
        case 0: s = w0; break; case 1: s = w1; break; case 2: s = w2; break;
        case 3: s = w3; break; case 4: s = w4; break; case 5: s = w5; break;
        case 6: s = w6; break; case 7: s = w7; break; case 8: s = w8; break;
        case 9: s = w9; break; case 10: s = w10; break; case 11: s = w11; break;
        default: s = w12; break;
    }
    WT[idx] = f2bf(s[(size_t)k * wd_ldw[d] + wd_coff[d] + n]);
}

// ---- fused bias vectors ----
__global__ void prep_bias_kernel(const float* sfk_b, const float* sfv_b,
                                 const float* tq_b, const float* tk_b, const float* tv_b,
                                 float* kvb, float* qkvb)
{
    int i = blockIdx.x * 256 + threadIdx.x;
    if (i < 512) kvb[i] = i < 256 ? sfk_b[i] : sfv_b[i - 256];
    if (i < 3072) {
        int h = i / 768, j = i - h * 768;
        qkvb[i] = j < 256 ? tq_b[h * 256 + j]
                : (j < 512 ? tk_b[h * 256 + j - 256] : tv_b[h * 256 + j - 512]);
    }
}

// ---------------- MFMA bf16 GEMM: C[M,N] = A[M,K] @ WT^T (+bias) ----------------
// A bf16 [M,K]; WT bf16 [N,K] row-major. 128x128 tile, BK=64, 4 waves 2x2.
// T2 XOR-swizzled LDS [128][64] (16B-granule ^ (row&7)) + T14 reg-prefetch pipeline
// + XCD-bijective block swizzle. Numerics identical to R5/R7 path.
template <typename OT>
__global__ __launch_bounds__(256)
void mgemm_kernel(const u16* __restrict__ A, int lda,
                  const u16* __restrict__ WT,
                  const float* __restrict__ bias,
                  OT* __restrict__ C, int ldc,
                  int M, int N, int K)
{
    __shared__ __align__(16) u16 As[8192];   // [128 rows][8 granules][8 u16]
    __shared__ __align__(16) u16 Bs[8192];
    const int t = threadIdx.x;
    const int wid = t >> 6, lane = t & 63;
    const int wr = wid >> 1, wc = wid & 1;
    const int lr = lane & 15, lg = lane >> 4;
    // XCD-bijective swizzle (m204)
    const int gx = gridDim.x;
    const int nwg = gx * gridDim.y;
    const int orig = blockIdx.y * gx + blockIdx.x;
    const int q8 = nwg >> 3, r8 = nwg & 7;
    const int xcd = orig & 7, oidx = orig >> 3;
    const int swzb = (xcd < r8 ? xcd * (q8 + 1) : r8 * (q8 + 1) + (xcd - r8) * q8) + oidx;
    const int row0 = (swzb / gx) * 128, col0 = (swzb % gx) * 128;

    const int sr = t >> 1;              // stage row 0..127
    const int sg0 = (t & 1) * 4;        // granule base 0 or 4
    const bool avalid = (row0 + sr) < M;
    const u16* aptr = &A[(size_t)min(row0 + sr, M - 1) * lda];
    const u16* bptr = &WT[(size_t)(col0 + sr) * K];
    const int swr = (sr & 7);           // write swizzle key
    f32x4 acc[4][4] = {};
    bf16x8 ra[4], rb[4];
    const bf16x8 z = {0, 0, 0, 0, 0, 0, 0, 0};

    auto gload = [&](int k0) {
#pragma unroll
        for (int j = 0; j < 4; ++j) {
            ra[j] = avalid ? *(const bf16x8*)&aptr[k0 + (sg0 + j) * 8] : z;
            rb[j] = *(const bf16x8*)&bptr[k0 + (sg0 + j) * 8];
        }
    };
    auto swrite = [&]() {
#pragma unroll
        for (int j = 0; j < 4; ++j) {
            const int g = (sg0 + j) ^ swr;
            *(bf16x8*)&As[(sr * 8 + g) * 8] = ra[j];
            *(bf16x8*)&Bs[(sr * 8 + g) * 8] = rb[j];
        }
    };
    auto compute = [&]() {
#pragma unroll
        for (int kk = 0; kk < 2; ++kk) {
            bf16x8 af[4], bfr[4];
#pragma unroll
            for (int m = 0; m < 4; ++m) {
                const int r = wr * 64 + m * 16 + lr;
                af[m] = *(const bf16x8*)&As[(r * 8 + ((kk * 4 + lg) ^ (r & 7))) * 8];
            }
#pragma unroll
            for (int n = 0; n < 4; ++n) {
                const int r = wc * 64 + n * 16 + lr;
                bfr[n] = *(const bf16x8*)&Bs[(r * 8 + ((kk * 4 + lg) ^ (r & 7))) * 8];
            }
#pragma unroll
            for (int m = 0; m < 4; ++m)
#pragma unroll
                for (int n = 0; n < 4; ++n)
                    acc[m][n] = __builtin_amdgcn_mfma_f32_16x16x32_bf16(af[m], bfr[n], acc[m][n], 0, 0, 0);
        }
    };

    gload(0);
    swrite();
    __syncthreads();
    for (int k0 = 64; k0 < K; k0 += 64) {
        gload(k0);          // issue next-tile loads; land under MFMA below
        compute();          // consume current LDS tile
        __syncthreads();    // all reads of current tile done
        swrite();           // write prefetched tile
        __syncthreads();
    }
    compute();

#pragma unroll
    for (int m = 0; m < 4; ++m) {
#pragma unroll
        for (int r = 0; r < 4; ++r) {
            int row = row0 + wr * 64 + m * 16 + lg * 4 + r;
            if (row >= M) continue;
#pragma unroll
            for (int n = 0; n < 4; ++n) {
                int col = col0 + wc * 64 + n * 16 + lr;
                float v = acc[m][n][r];
                if (bias) v += bias[col];
                if constexpr (sizeof(OT) == 4) C[(size_t)row * ldc + col] = v;
                else C[(size_t)row * ldc + col] = f2bf(v);
            }
        }
    }
}

// ---------------- side fusion attention: one wave per wine, T=4, kv interleaved ----------------
__global__ __launch_bounds__(256)
void side_attn_kernel(const u16* __restrict__ q, const u16* __restrict__ kv,
                      u16* __restrict__ ao, int NI)
{
    const int wid = threadIdx.x >> 6, lane = threadIdx.x & 63;
    const int n = blockIdx.x * 4 + wid;
    if (n >= NI) return;
    const ushort4 qu = *(const ushort4*)&q[(size_t)n * 256 + lane * 4];
    const float q0 = bf2f(qu.x), q1 = bf2f(qu.y), q2 = bf2f(qu.z), q3 = bf2f(qu.w);
    float logit[4];
#pragma unroll
    for (int tk = 0; tk < 4; ++tk) {
        const ushort4 ku = *(const ushort4*)&kv[((size_t)n * 4 + tk) * 512 + lane * 4];
        float p = q0 * bf2f(ku.x) + q1 * bf2f(ku.y) + q2 * bf2f(ku.z) + q3 * bf2f(ku.w);
        logit[tk] = wave_sum(p) * (1.f / 16.f);
    }
    float mx = fmaxf(fmaxf(logit[0], logit[1]), fmaxf(logit[2], logit[3]));
    float e[4], den = 0.f;
#pragma unroll
    for (int tk = 0; tk < 4; ++tk) { e[tk] = __expf(logit[tk] - mx); den += e[tk]; }
    const float inv = 1.f / den;
    float o0 = 0.f, o1 = 0.f, o2 = 0.f, o3 = 0.f;
#pragma unroll
    for (int tk = 0; tk < 4; ++tk) {
        const ushort4 vu = *(const ushort4*)&kv[((size_t)n * 4 + tk) * 512 + 256 + lane * 4];
        const float w = e[tk] * inv;
        o0 = fmaf(w, bf2f(vu.x), o0); o1 = fmaf(w, bf2f(vu.y), o1);
        o2 = fmaf(w, bf2f(vu.z), o2); o3 = fmaf(w, bf2f(vu.w), o3);
    }
    ushort4 o;
    o.x = f2bf(o0); o.y = f2bf(o1); o.z = f2bf(o2); o.w = f2bf(o3);
    *(ushort4*)&ao[(size_t)n * 256 + lane * 4] = o;
}

// ---------------- deterministic CSR build: hist + scan + atomic fill + per-node sort ----------------
__global__ void degw_kernel(const int* __restrict__ dst, const u8* __restrict__ keep,
                            float* __restrict__ degw, int E)
{
    int e = blockIdx.x * 256 + threadIdx.x;
    if (e >= E) return;
    if (keep[e]) atomicAdd(&degw[dst[e]], 1.f);
}

__global__ void dinv_kernel(const float* __restrict__ degw, float* __restrict__ dinv, int N)
{
    int n = blockIdx.x * 256 + threadIdx.x;
    if (n < N) dinv[n] = rsqrtf(degw[n] + 1.f);
}

__global__ void count_kernel(const int* __restrict__ dst, int* __restrict__ cnt, int E)
{
    int e = blockIdx.x * 256 + threadIdx.x;
    if (e < E) atomicAdd(&cnt[dst[e]], 1);
}

__global__ __launch_bounds__(1024)
void scan_kernel(const int* __restrict__ cnt, int* __restrict__ rs, int n)
{
    __shared__ int wsum[17];
    __shared__ int s_run;
    const int t = threadIdx.x, lane = t & 63, wid = t >> 6;
    if (t == 0) s_run = 0;
    __syncthreads();
    for (int base = 0; base < n; base += 1024) {
        int i = base + t;
        int v = (i < n) ? cnt[i] : 0;
        int x = v;
#pragma unroll
        for (int off = 1; off < 64; off <<= 1) {
            int y = __shfl_up(x, off);
            if (lane >= off) x += y;
        }
        if (lane == 63) wsum[wid] = x;
        __syncthreads();
        if (t == 0) {
            int a = 0;
            for (int j = 0; j < 16; ++j) { int tmp = wsum[j]; wsum[j] = a; a += tmp; }
            wsum[16] = a;
        }
        __syncthreads();
        if (i < n) rs[i] = s_run + wsum[wid] + x - v;
        __syncthreads();
        if (t == 0) s_run += wsum[16];
        __syncthreads();
    }
    if (t == 0) rs[n] = s_run;
}

__global__ void fill_kernel(const int* __restrict__ dst, const int* __restrict__ rs,
                            int* __restrict__ cursor, int* __restrict__ eid, int E)
{
    int e = blockIdx.x * 256 + threadIdx.x;
    if (e >= E) return;
    int d = dst[e];
    int p = atomicAdd(&cursor[d], 1);
    eid[rs[d] + p] = e;
}

// per-node insertion sort -> segment content ascending edge id (deterministic)
__global__ void sort_kernel(const int* __restrict__ rs, int* __restrict__ eid, int N)
{
    int n = blockIdx.x * 256 + threadIdx.x;
    if (n >= N) return;
    const int b = rs[n], len = rs[n + 1] - b;
    for (int i = 1; i < len; ++i) {
        int key = eid[b + i];
        int j = i - 1;
        while (j >= 0 && eid[b + j] > key) { eid[b + j + 1] = eid[b + j]; --j; }
        eid[b + j + 1] = key;
    }
}

// ---------------- GCN aggregate; reads bf16 xw, writes bf16 x ----------------
__global__ __launch_bounds__(256)
void gcn_kernel(const u16* __restrict__ xw, const int* __restrict__ src,
                const u8* __restrict__ keep,
                const int* __restrict__ rs, const int* __restrict__ eid,
                const float* __restrict__ dinv, const float* __restrict__ gb,
                u16* __restrict__ xout, int N)
{
    const int n = blockIdx.x;
    const int d = threadIdx.x;
    const float di = dinv[n];
    float acc = bf2f(xw[(size_t)n * 256 + d]) * di * di;
    const int e0 = rs[n], e1 = rs[n + 1];
    for (int i = e0; i < e1; ++i) {
        const int e = eid[i];
        if (!keep[e]) continue;
        const int s = src[e];
        acc = fmaf(bf2f(xw[(size_t)s * 256 + d]), dinv[s] * di, acc);
    }
    xout[(size_t)n * 256 + d] = f2bf(acc + gb[d]);
}

// ---------------- TransformerConv, one head from fused qkv [n][768] ----------------
__global__ __launch_bounds__(256)
void tconv_head_kernel(const u16* __restrict__ qkv,
                       const int* __restrict__ src, const u8* __restrict__ keep,
                       const int* __restrict__ rs, const int* __restrict__ eid,
                       float* __restrict__ xacc, int N)
{
    const int wid = threadIdx.x >> 6, lane = threadIdx.x & 63;
    const int n = blockIdx.x * 4 + wid;
    if (n >= N) return;
    const ushort4 qu = *(const ushort4*)&qkv[(size_t)n * 768 + lane * 4];
    const float q0 = bf2f(qu.x), q1 = bf2f(qu.y), q2 = bf2f(qu.z), q3 = bf2f(qu.w);
    const int e0 = rs[n], e1 = rs[n + 1];
    float m = -1e30f, den = 0.f;
    float a0 = 0.f, a1 = 0.f, a2 = 0.f, a3 = 0.f;
    for (int i = e0; i < e1; ++i) {
        const int e = eid[i];
        if (!keep[e]) continue;
        const int s = src[e];
        const ushort4 ku = *(const ushort4*)&qkv[(size_t)s * 768 + 256 + lane * 4];
        float p = q0 * bf2f(ku.x) + q1 * bf2f(ku.y) + q2 * bf2f(ku.z) + q3 * bf2f(ku.w);
        p = wave_sum(p);
        const float lg = p * (1.f / 16.f);
        if (lg > m) {
            const float sc = __expf(m - lg);
            den *= sc; a0 *= sc; a1 *= sc; a2 *= sc; a3 *= sc;
            m = lg;
        }
        const float w = __expf(lg - m);
        den += w;
        const ushort4 vu = *(const ushort4*)&qkv[(size_t)s * 768 + 512 + lane * 4];
        a0 = fmaf(w, bf2f(vu.x), a0); a1 = fmaf(w, bf2f(vu.y), a1);
        a2 = fmaf(w, bf2f(vu.z), a2); a3 = fmaf(w, bf2f(vu.w), a3);
    }
    const float inv = 0.25f / fmaxf(den, 1e-16f);
    float4* p4 = (float4*)&xacc[(size_t)n * 256 + lane * 4];
    float4 cur = *p4;
    cur.x += a0 * inv; cur.y += a1 * inv; cur.z += a2 * inv; cur.w += a3 * inv;
    *p4 = cur;
}

// ---------------- recon loss partials ----------------
__global__ __launch_bounds__(256)
void recon_kernel(const float* __restrict__ x, const u8* __restrict__ mask,
                  const float* __restrict__ aeb,
                  float* __restrict__ rblkS, float* __restrict__ rblkC, int N)
{
    const int total = N * 256;
    float s = 0.f, c = 0.f;
    for (int idx = blockIdx.x * 256 + threadIdx.x; idx < total; idx += gridDim.x * 256) {
        const int n = idx >> 8, d = idx & 255;
        if (mask[n]) {
            const float diff = aeb[d] - x[idx];
            s = fmaf(diff, diff, s);
            if (d == 0) c += 1.f;
        }
    }
    s = wave_sum(s); c = wave_sum(c);
    __shared__ float ss[4], cc[4];
    const int lane = threadIdx.x & 63, wid = threadIdx.x >> 6;
    if (lane == 0) { ss[wid] = s; cc[wid] = c; }
    __syncthreads();
    if (threadIdx.x == 0) {
        rblkS[blockIdx.x] = ss[0] + ss[1] + ss[2] + ss[3];
        rblkC[blockIdx.x] = cc[0] + cc[1] + cc[2] + cc[3];
    }
}

// ---------------- pair scores + per-block edge-pred partials ----------------
__global__ __launch_bounds__(256)
void score_kernel(const float* __restrict__ x, const int* __restrict__ user,
                  const int* __restrict__ wine,
                  const float* __restrict__ epw, const float* __restrict__ epb,
                  const float* __restrict__ fcw, const float* __restrict__ fcb,
                  float* __restrict__ out, float* __restrict__ sblk, int B)
{
    __shared__ float sep[4];
    const int wid = threadIdx.x >> 6, lane = threadIdx.x & 63;
    const int b = blockIdx.x * 4 + wid;
    if (b < B) {
        const size_t u = (size_t)user[b];
        const size_t w = (size_t)wine[b] + NU_C;
        const float4 xu = *(const float4*)&x[u * 256 + lane * 4];
        const float4 xw = *(const float4*)&x[w * 256 + lane * 4];
        const float4 e1 = *(const float4*)&epw[lane * 4];
        const float4 e2 = *(const float4*)&epw[256 + lane * 4];
        const float4 f1 = *(const float4*)&fcw[lane * 4];
        const float4 f2 = *(const float4*)&fcw[256 + lane * 4];
        float pep = xu.x * e1.x + xu.y * e1.y + xu.z * e1.z + xu.w * e1.w
                  + xw.x * e2.x + xw.y * e2.y + xw.z * e2.z + xw.w * e2.w;
        float pfc = xu.x * f1.x + xu.y * f1.y + xu.z * f1.z + xu.w * f1.w
                  + xw.x * f2.x + xw.y * f2.y + xw.z * f2.z + xw.w * f2.w;
        pep = wave_sum(pep); pfc = wave_sum(pfc);
        if (lane == 0) {
            const float es = 1.f / (1.f + __expf(-(pep + epb[0])));
            sep[wid] = (es - 1.f) * (es - 1.f);
            out[b] = 1.f / (1.f + __expf(-(pfc + fcb[0]))) * 4.f + 1.f;
        }
    } else if (lane == 0) {
        sep[wid] = 0.f;
    }
    __syncthreads();
    if (threadIdx.x == 0) sblk[blockIdx.x] = sep[0] + sep[1] + sep[2] + sep[3];
}

__global__ __launch_bounds__(1024)
void final_reduce_kernel(const float* __restrict__ rblkS, const float* __restrict__ rblkC,
                         const float* __restrict__ sblk, float* __restrict__ out, int B)
{
    const int t = threadIdx.x, lane = t & 63, wid = t >> 6;
    float s = rblkS[t] + rblkS[t + 1024];
    float c = rblkC[t] + rblkC[t + 1024];
    float p = sblk[t] + sblk[t + 1024];
    s = wave_sum(s); c = wave_sum(c); p = wave_sum(p);
    __shared__ float ss[16], cc[16], pp[16];
    if (lane == 0) { ss[wid] = s; cc[wid] = c; pp[wid] = p; }
    __syncthreads();
    if (t == 0) {
        float S = 0.f, C = 0.f, P = 0.f;
        for (int i = 0; i < 16; ++i) { S += ss[i]; C += cc[i]; P += pp[i]; }
        out[B] = S / (C * 256.f);
        out[B + 1] = P / (float)B;
    }
}

extern "C" void kernel_launch(void* const* d_in, const int* in_sizes, int n_in,
                              void* d_out, int out_size, void* d_ws, size_t ws_size,
                              hipStream_t stream)
{
    const int* user = (const int*)d_in[0];
    const int* wine = (const int*)d_in[1];
    const int* e_src = (const int*)d_in[2];
    const int* e_dst = e_src + E_C;
    const void* keep_raw  = d_in[3];
    const void* nmask_raw = d_in[4];
    const float* user_emb = (const float*)d_in[5];
    const float* wine_emb = (const float*)d_in[6];
    const float* up_w = (const float*)d_in[7];
    const float* up_b = (const float*)d_in[8];
    const float* wp_w = (const float*)d_in[9];
    const float* wp_b = (const float*)d_in[10];
    const float* sf_proj_w = (const float*)d_in[11];
    const float* sf_proj_b = (const float*)d_in[12];
    const float* sf_q_w = (const float*)d_in[13];
    const float* sf_q_b = (const float*)d_in[14];
    const float* sf_k_w = (const float*)d_in[15];
    const float* sf_k_b = (const float*)d_in[16];
    const float* sf_v_w = (const float*)d_in[17];
    const float* sf_v_b = (const float*)d_in[18];
    const float* sf_o_w = (const float*)d_in[19];
    const float* sf_o_b = (const float*)d_in[20];
    const float* sf_fc_w = (const float*)d_in[21];
    const float* sf_fc_b = (const float*)d_in[22];
    const float* g_w = (const float*)d_in[23];
    const float* g_b = (const float*)d_in[24];
    const float* t_q_w = (const float*)d_in[25];
    const float* t_q_b = (const float*)d_in[26];
    const float* t_k_w = (const float*)d_in[27];
    const float* t_k_b = (const float*)d_in[28];
    const float* t_v_w = (const float*)d_in[29];
    const float* t_v_b = (const float*)d_in[30];
    const float* t_skip_w = (const float*)d_in[31];
    const float* t_skip_b = (const float*)d_in[32];
    const float* fc_w = (const float*)d_in[33];
    const float* fc_b = (const float*)d_in[34];
    const float* ae_b = (const float*)d_in[36];
    const float* ep_w = (const float*)d_in[37];
    const float* ep_b = (const float*)d_in[38];
    const float* wsf = (const float*)d_in[39];
    float* out = (float*)d_out;
    char* ws = (char*)d_ws;

    size_t off = 0;
    auto take = [&](size_t b) { size_t r = off; off += (b + 255) & ~(size_t)255; return r; };
    const size_t o_xb     = take((size_t)N_C * 256 * 2);
    const size_t o_cnt    = take((size_t)N_C * 4);     // zero region start
    const size_t o_degw   = take((size_t)N_C * 4);
    const size_t o_cursor = take((size_t)N_C * 4);
    const size_t o_scal   = take(256);                 // flag
    const size_t o_rowst  = take((size_t)(N_C + 1) * 4);
    const size_t o_dinv   = take((size_t)N_C * 4);
    const size_t o_eid    = take((size_t)E_C * 4);
    const size_t o_kmask  = take((size_t)E_C);
    const size_t o_nmask  = take((size_t)N_C);
    const size_t o_rblkS  = take(2048 * 4);
    const size_t o_rblkC  = take(2048 * 4);
    const size_t o_sblk   = take(2048 * 4);
    const size_t o_wt     = take((size_t)WT_ELEMS * 2);
    const size_t o_bias   = take(3584 * 4);
    const size_t ARENA    = 102400000;
    const size_t o_arena  = take(ARENA);
    const size_t NEED = off;

    if (ws_size < NEED) {
        fillval_kernel<<<dim3((out_size + 255) / 256), 256, 0, stream>>>(
            out, out_size, (float)((double)ws_size / (1024.0 * 1024.0)));
        return;
    }

    u16*   xb     = (u16*)  (ws + o_xb);
    int*   cnt    = (int*)  (ws + o_cnt);
    float* degw   = (float*)(ws + o_degw);
    int*   cursor = (int*)  (ws + o_cursor);
    int*   flag   = (int*)  (ws + o_scal);
    int*   rowst  = (int*)  (ws + o_rowst);
    float* dinvb  = (float*)(ws + o_dinv);
    int*   eid    = (int*)  (ws + o_eid);
    u8*    kmask  = (u8*)   (ws + o_kmask);
    u8*    nmaskb = (u8*)   (ws + o_nmask);
    float* rblkS  = (float*)(ws + o_rblkS);
    float* rblkC  = (float*)(ws + o_rblkC);
    float* sblk   = (float*)(ws + o_sblk);
    u16*   WT     = (u16*)  (ws + o_wt);
    float* kvb    = (float*)(ws + o_bias);
    float* qkvb   = kvb + 512;

    // WT region offsets (elements)
    u16* wt_up   = WT + 0;
    u16* wt_wp   = WT + 16384;
    u16* wt_proj = WT + 32768;
    u16* wt_sfq  = WT + 49152;
    u16* wt_sfkv = WT + 114688;   // [512,256]
    u16* wt_sfo  = WT + 245760;
    u16* wt_sffc = WT + 311296;   // [256,512]
    u16* wt_g    = WT + 442368;
    u16* wt_skip = WT + 507904;
    u16* wt_qkv  = WT + 573440;   // per head h: +h*196608, [768,256]

    // arena overlays:
    u16* ue16  = (u16*)(ws + o_arena);                    //  3.84 MB
    u16* we16  = (u16*)(ws + o_arena + 3840000);          //  1.28 MB
    u16* wsf16 = (u16*)(ws + o_arena + 5120000);          //  5.12 MB
    u16* cat   = (u16*)(ws + o_arena + 10240000);         // [NI,512]
    u16* side  = (u16*)(ws + o_arena + 20480000);         // [NI*4,256]
    u16* qbuf  = (u16*)(ws + o_arena + 40960000);         // [NI,256]
    u16* kvbuf = (u16*)(ws + o_arena + 46080000);         // [NI*4,512]
    u16* aobuf = (u16*)(ws + o_arena + 87040000);         // [NI,256]
    u16* xw    = (u16*)(ws + o_arena);                    // bf16 [N,256] (phase B)
    u16* qkvh  = (u16*)(ws + o_arena);                    // [N,768] bf16 (phase C)
    float* xacc = (float*)(ws + o_arena + 61440000);      // f32 [N,256]

    const int zero_words = (3 * N_C * 4 + 256) / 4;
    zero_kernel<<<dim3((zero_words + 255) / 256), 256, 0, stream>>>((unsigned int*)cnt, zero_words);

    detect_kernel<<<dim3((E_C / 4 + 255) / 256), 256, 0, stream>>>((const unsigned int*)keep_raw, E_C / 4, flag);
    conv_mask_kernel<<<dim3((E_C + 255) / 256), 256, 0, stream>>>(keep_raw, kmask, E_C, flag);
    conv_mask_kernel<<<dim3((N_C + 255) / 256), 256, 0, stream>>>(nmask_raw, nmaskb, N_C, flag);

    // ---- prep: convert embeddings, transpose weights, fuse biases ----
    conv3_kernel<<<dim3(2048), 256, 0, stream>>>(user_emb, NU_C * 16, wine_emb, NI_C * 16,
                                                 wsf, N_C * 16, ue16, we16, wsf16);
    wtrans_kernel<<<dim3(WT_ELEMS / 256), 256, 0, stream>>>(up_w, wp_w, sf_proj_w, sf_q_w,
        sf_k_w, sf_v_w, sf_o_w, sf_fc_w, g_w, t_skip_w, t_q_w, t_k_w, t_v_w, WT);
    prep_bias_kernel<<<dim3(12), 256, 0, stream>>>(sf_k_b, sf_v_b, t_q_b, t_k_b, t_v_b, kvb, qkvb);

    // ---- phase A ----
    mgemm_kernel<u16><<<dim3(2, 235), 256, 0, stream>>>(ue16, 64, wt_up, up_b, xb, 256, NU_C, 256, 64);
    mgemm_kernel<u16><<<dim3(2, 79), 256, 0, stream>>>(we16, 64, wt_wp, wp_b, cat, 512, NI_C, 256, 64);
    mgemm_kernel<u16><<<dim3(2, 313), 256, 0, stream>>>(wsf16, 64, wt_proj, sf_proj_b, side, 256, N_C, 256, 64);
    mgemm_kernel<u16><<<dim3(2, 79), 256, 0, stream>>>(cat, 512, wt_sfq, sf_q_b, qbuf, 256, NI_C, 256, 256);
    mgemm_kernel<u16><<<dim3(4, 313), 256, 0, stream>>>(side, 256, wt_sfkv, kvb, kvbuf, 512, N_C, 512, 256);
    side_attn_kernel<<<dim3(2500), 256, 0, stream>>>(qbuf, kvbuf, aobuf, NI_C);
    mgemm_kernel<u16><<<dim3(2, 79), 256, 0, stream>>>(aobuf, 256, wt_sfo, sf_o_b, cat + 256, 512, NI_C, 256, 256);
    mgemm_kernel<u16><<<dim3(2, 79), 256, 0, stream>>>(cat, 512, wt_sffc, sf_fc_b, xb + (size_t)NU_C * 256, 256, NI_C, 256, 512);

    // ---- deterministic CSR (atomic fill + per-node sort) ----
    degw_kernel<<<dim3((E_C + 255) / 256), 256, 0, stream>>>(e_dst, kmask, degw, E_C);
    dinv_kernel<<<dim3((N_C + 255) / 256), 256, 0, stream>>>(degw, dinvb, N_C);
    count_kernel<<<dim3((E_C + 255) / 256), 256, 0, stream>>>(e_dst, cnt, E_C);
    scan_kernel<<<dim3(1), 1024, 0, stream>>>(cnt, rowst, N_C);
    fill_kernel<<<dim3((E_C + 255) / 256), 256, 0, stream>>>(e_dst, rowst, cursor, eid, E_C);
    sort_kernel<<<dim3((N_C + 255) / 256), 256, 0, stream>>>(rowst, eid, N_C);

    // ---- phase B: GCN ----
    mgemm_kernel<u16><<<dim3(2, 313), 256, 0, stream>>>(xb, 256, wt_g, nullptr, xw, 256, N_C, 256, 256);
    gcn_kernel<<<dim3(N_C), 256, 0, stream>>>(xw, e_src, kmask, rowst, eid, dinvb, g_b, xb, N_C);

    // ---- phase C: skip + per-head fused QKV + tconv ----
    mgemm_kernel<float><<<dim3(2, 313), 256, 0, stream>>>(xb, 256, wt_skip, t_skip_b, xacc, 256, N_C, 256, 256);
    for (int h = 0; h < 4; ++h) {
        mgemm_kernel<u16><<<dim3(6, 313), 256, 0, stream>>>(xb, 256, wt_qkv + h * 196608,
                                                            qkvb + h * 768, qkvh, 768, N_C, 768, 256);
        tconv_head_kernel<<<dim3(N_C / 4), 256, 0, stream>>>(qkvh, e_src, kmask, rowst, eid, xacc, N_C);
    }

    // ---- losses + scores ----
    recon_kernel<<<dim3(2048), 256, 0, stream>>>(xacc, nmaskb, ae_b, rblkS, rblkC, N_C);
    score_kernel<<<dim3(2048), 256, 0, stream>>>(xacc, user, wine, ep_w, ep_b, fc_w, fc_b, out, sblk, B_C);
    final_reduce_kernel<<<dim3(1), 1024, 0, stream>>>(rblkS, rblkC, sblk, out, B_C);
}

// Round 9
// 700.038 us; speedup vs baseline: 1.1526x; 1.1526x over previous
//
#include <hip/hip_runtime.h>
#include <stdint.h>

typedef unsigned short u16;
typedef unsigned char u8;
typedef __attribute__((ext_vector_type(8))) short bf16x8;
typedef __attribute__((ext_vector_type(4))) float f32x4;

#define NU_C 30000
#define NI_C 10000
#define N_C  40000
#define E_C  100000
#define B_C  8192

static __device__ __forceinline__ float bf2f(u16 u) {
    union { unsigned int i; float f; } c; c.i = ((unsigned int)u) << 16; return c.f;
}
static __device__ __forceinline__ u16 f2bf(float f) {
    union { float f; unsigned int i; } c; c.f = f;
    return (u16)((c.i + 0x7FFFu + ((c.i >> 16) & 1u)) >> 16);
}
static __device__ __forceinline__ float wave_sum(float v) {
#pragma unroll
    for (int off = 32; off > 0; off >>= 1) v += __shfl_xor(v, off);
    return v;
}

__global__ void zero_kernel(unsigned int* p, int n) {
    int i = blockIdx.x * 256 + threadIdx.x;
    if (i < n) p[i] = 0u;
}
__global__ void fillval_kernel(float* p, int n, float v) {
    int i = blockIdx.x * 256 + threadIdx.x;
    if (i < n) p[i] = v;
}

// ---- bool-layout detection ----
__global__ void detect_kernel(const unsigned int* a, int n, int* flag) {
    int i = blockIdx.x * 256 + threadIdx.x;
    if (i >= n) return;
    unsigned int v = a[i];
    int f = 0;
    if (v > 1u) f |= 1;
    if (v != 0u && v != 0x3F800000u) f |= 2;
    if (f) atomicOr(flag, f);
}
__global__ void conv_mask_kernel(const void* raw, u8* outm, int n, const int* flag) {
    int i = blockIdx.x * 256 + threadIdx.x;
    if (i >= n) return;
    const int f = *flag;
    u8 r;
    if ((f & 1) == 0)      r = ((const int*)raw)[i] != 0;
    else if ((f & 2) == 0) r = ((const float*)raw)[i] != 0.f;
    else                   r = ((const u8*)raw)[i] != 0;
    outm[i] = r;
}

// ---- f32 -> bf16 conversion for the three embedding inputs ----
__global__ void conv3_kernel(const float* __restrict__ a, int na4,
                             const float* __restrict__ b, int nb4,
                             const float* __restrict__ c, int nc4,
                             u16* __restrict__ oa, u16* __restrict__ ob, u16* __restrict__ oc)
{
    int tot = na4 + nb4 + nc4;
    for (int i = blockIdx.x * 256 + threadIdx.x; i < tot; i += gridDim.x * 256) {
        const float* s; u16* o; int j = i;
        if (j < na4) { s = a; o = oa; }
        else if ((j -= na4) < nb4) { s = b; o = ob; }
        else { j -= nb4; s = c; o = oc; }
        float4 v = *(const float4*)&s[(size_t)j * 4];
        ushort4 r;
        r.x = f2bf(v.x); r.y = f2bf(v.y); r.z = f2bf(v.z); r.w = f2bf(v.w);
        *(ushort4*)&o[(size_t)j * 4] = r;
    }
}

// ---- batched weight transpose+convert: WT[n*K + k] = bf16(W[k*ldw + coloff + n]) ----
#define WT_ELEMS 1359872
__device__ const int wd_prefix[23] = {0,16384,32768,49152,114688,180224,245760,311296,442368,
    507904,573440,638976,704512,770048,835584,901120,966656,1032192,1097728,1163264,1228800,
    1294336,1359872};
__device__ const u8  wd_src[22]  = {0,1,2,3,4,5,6,7,8,9,10,11,12,10,11,12,10,11,12,10,11,12};
__device__ const short wd_ldw[22]= {256,256,256,256,256,256,256,256,256,256,
    1024,1024,1024,1024,1024,1024,1024,1024,1024,1024,1024,1024};
__device__ const short wd_coff[22]={0,0,0,0,0,0,0,0,0,0, 0,0,0, 256,256,256, 512,512,512, 768,768,768};
__device__ const short wd_kmask[22]={63,63,63,255,255,255,255,511,255,255,
    255,255,255,255,255,255,255,255,255,255,255,255};
__device__ const u8  wd_ksh[22] = {6,6,6,8,8,8,8,9,8,8, 8,8,8,8,8,8,8,8,8,8,8,8};

__global__ __launch_bounds__(256)
void wtrans_kernel(const float* w0, const float* w1, const float* w2, const float* w3,
                   const float* w4, const float* w5, const float* w6, const float* w7,
                   const float* w8, const float* w9, const float* w10, const float* w11,
                   const float* w12, u16* __restrict__ WT)
{
    int idx = blockIdx.x * 256 + threadIdx.x;
    if (idx >= WT_ELEMS) return;
    int d = 0;
    while (wd_prefix[d + 1] <= idx) ++d;
    const int local = idx - wd_prefix[d];
    const int k = local & wd_kmask[d];
    const int n = local >> wd_ksh[d];
    const float* s;
    switch (wd_src[d]) {
        case 0: s = w0; break; case 1: s = w1; break; case 2: s = w2; break;
        case 3: s = w3; break; case 4: s = w4; break; case 5: s = w5; break;
        case 6: s = w6; break; case 7: s = w7; break; case 8: s = w8; break;
        case 9: s = w9; break; case 10: s = w10; break; case 11: s = w11; break;
        default: s = w12; break;
    }
    WT[idx] = f2bf(s[(size_t)k * wd_ldw[d] + wd_coff[d] + n]);
}

// ---- fused bias vectors ----
__global__ void prep_bias_kernel(const float* sfk_b, const float* sfv_b,
                                 const float* tq_b, const float* tk_b, const float* tv_b,
                                 float* kvb, float* qkvb)
{
    int i = blockIdx.x * 256 + threadIdx.x;
    if (i < 512) kvb[i] = i < 256 ? sfk_b[i] : sfv_b[i - 256];
    if (i < 3072) {
        int h = i / 768, j = i - h * 768;
        qkvb[i] = j < 256 ? tq_b[h * 256 + j]
                : (j < 512 ? tk_b[h * 256 + j - 256] : tv_b[h * 256 + j - 512]);
    }
}

// ---------------- MFMA bf16 GEMM: C[M,N] = A[M,K] @ WT^T (+bias) ----------------
// A bf16 [M,K]; WT bf16 [N,K] row-major. 256x128 tile, BK=64, 8 waves as 4x2
// (each wave 64x64). R7-validated single-stage loop; XCD-bijective block swizzle.
template <typename OT>
__global__ __launch_bounds__(512)
void mgemm_kernel(const u16* __restrict__ A, int lda,
                  const u16* __restrict__ WT,
                  const float* __restrict__ bias,
                  OT* __restrict__ C, int ldc,
                  int M, int N, int K)
{
    __shared__ __align__(16) u16 As[256][72];
    __shared__ __align__(16) u16 Bs[128][72];
    const int t = threadIdx.x;
    const int wid = t >> 6, lane = t & 63;
    const int wr = wid >> 1, wc = wid & 1;        // 4 x 2 wave grid
    const int lr = lane & 15, lg = lane >> 4;
    // XCD-bijective swizzle (m204)
    const int gx = gridDim.x;
    const int nwg = gx * gridDim.y;
    const int orig = blockIdx.y * gx + blockIdx.x;
    const int q8 = nwg >> 3, r8 = nwg & 7;
    const int xcd = orig & 7, oidx = orig >> 3;
    const int swzb = (xcd < r8 ? xcd * (q8 + 1) : r8 * (q8 + 1) + (xcd - r8) * q8) + oidx;
    const int row0 = (swzb / gx) * 256, col0 = (swzb % gx) * 128;
    const int sra = t >> 1, sha = (t & 1) * 32;   // A stage: 2 threads/row, 256 rows
    const int srb = t >> 2, shb = (t & 3) * 16;   // B stage: 4 threads/row, 128 rows
    f32x4 acc[4][4] = {};

    for (int k0 = 0; k0 < K; k0 += 64) {
        {
            const int gr = row0 + sra;
            if (gr < M) {
                const u16* ap = &A[(size_t)gr * lda + k0 + sha];
#pragma unroll
                for (int j = 0; j < 4; ++j)
                    *(bf16x8*)&As[sra][sha + j * 8] = *(const bf16x8*)&ap[j * 8];
            } else {
                const bf16x8 z = {0, 0, 0, 0, 0, 0, 0, 0};
#pragma unroll
                for (int j = 0; j < 4; ++j)
                    *(bf16x8*)&As[sra][sha + j * 8] = z;
            }
        }
        {
            const u16* bp = &WT[(size_t)(col0 + srb) * K + k0 + shb];
#pragma unroll
            for (int j = 0; j < 2; ++j)
                *(bf16x8*)&Bs[srb][shb + j * 8] = *(const bf16x8*)&bp[j * 8];
        }
        __syncthreads();
#pragma unroll
        for (int kk = 0; kk < 2; ++kk) {
            bf16x8 af[4], bfr[4];
#pragma unroll
            for (int m = 0; m < 4; ++m)
                af[m] = *(const bf16x8*)&As[wr * 64 + m * 16 + lr][kk * 32 + lg * 8];
#pragma unroll
            for (int n = 0; n < 4; ++n)
                bfr[n] = *(const bf16x8*)&Bs[wc * 64 + n * 16 + lr][kk * 32 + lg * 8];
#pragma unroll
            for (int m = 0; m < 4; ++m)
#pragma unroll
                for (int n = 0; n < 4; ++n)
                    acc[m][n] = __builtin_amdgcn_mfma_f32_16x16x32_bf16(af[m], bfr[n], acc[m][n], 0, 0, 0);
        }
        __syncthreads();
    }
#pragma unroll
    for (int m = 0; m < 4; ++m) {
#pragma unroll
        for (int r = 0; r < 4; ++r) {
            int row = row0 + wr * 64 + m * 16 + lg * 4 + r;
            if (row >= M) continue;
#pragma unroll
            for (int n = 0; n < 4; ++n) {
                int col = col0 + wc * 64 + n * 16 + lr;
                float v = acc[m][n][r];
                if (bias) v += bias[col];
                if constexpr (sizeof(OT) == 4) C[(size_t)row * ldc + col] = v;
                else C[(size_t)row * ldc + col] = f2bf(v);
            }
        }
    }
}

// ---------------- side fusion attention: one wave per wine, T=4, kv interleaved ----------------
__global__ __launch_bounds__(256)
void side_attn_kernel(const u16* __restrict__ q, const u16* __restrict__ kv,
                      u16* __restrict__ ao, int NI)
{
    const int wid = threadIdx.x >> 6, lane = threadIdx.x & 63;
    const int n = blockIdx.x * 4 + wid;
    if (n >= NI) return;
    const ushort4 qu = *(const ushort4*)&q[(size_t)n * 256 + lane * 4];
    const float q0 = bf2f(qu.x), q1 = bf2f(qu.y), q2 = bf2f(qu.z), q3 = bf2f(qu.w);
    float logit[4];
#pragma unroll
    for (int tk = 0; tk < 4; ++tk) {
        const ushort4 ku = *(const ushort4*)&kv[((size_t)n * 4 + tk) * 512 + lane * 4];
        float p = q0 * bf2f(ku.x) + q1 * bf2f(ku.y) + q2 * bf2f(ku.z) + q3 * bf2f(ku.w);
        logit[tk] = wave_sum(p) * (1.f / 16.f);
    }
    float mx = fmaxf(fmaxf(logit[0], logit[1]), fmaxf(logit[2], logit[3]));
    float e[4], den = 0.f;
#pragma unroll
    for (int tk = 0; tk < 4; ++tk) { e[tk] = __expf(logit[tk] - mx); den += e[tk]; }
    const float inv = 1.f / den;
    float o0 = 0.f, o1 = 0.f, o2 = 0.f, o3 = 0.f;
#pragma unroll
    for (int tk = 0; tk < 4; ++tk) {
        const ushort4 vu = *(const ushort4*)&kv[((size_t)n * 4 + tk) * 512 + 256 + lane * 4];
        const float w = e[tk] * inv;
        o0 = fmaf(w, bf2f(vu.x), o0); o1 = fmaf(w, bf2f(vu.y), o1);
        o2 = fmaf(w, bf2f(vu.z), o2); o3 = fmaf(w, bf2f(vu.w), o3);
    }
    ushort4 o;
    o.x = f2bf(o0); o.y = f2bf(o1); o.z = f2bf(o2); o.w = f2bf(o3);
    *(ushort4*)&ao[(size_t)n * 256 + lane * 4] = o;
}

// ---------------- deterministic CSR build: hist + scan + atomic fill + per-node sort ----------------
__global__ void degw_kernel(const int* __restrict__ dst, const u8* __restrict__ keep,
                            float* __restrict__ degw, int E)
{
    int e = blockIdx.x * 256 + threadIdx.x;
    if (e >= E) return;
    if (keep[e]) atomicAdd(&degw[dst[e]], 1.f);
}

__global__ void dinv_kernel(const float* __restrict__ degw, float* __restrict__ dinv, int N)
{
    int n = blockIdx.x * 256 + threadIdx.x;
    if (n < N) dinv[n] = rsqrtf(degw[n] + 1.f);
}

__global__ void count_kernel(const int* __restrict__ dst, int* __restrict__ cnt, int E)
{
    int e = blockIdx.x * 256 + threadIdx.x;
    if (e < E) atomicAdd(&cnt[dst[e]], 1);
}

__global__ __launch_bounds__(1024)
void scan_kernel(const int* __restrict__ cnt, int* __restrict__ rs, int n)
{
    __shared__ int wsum[17];
    __shared__ int s_run;
    const int t = threadIdx.x, lane = t & 63, wid = t >> 6;
    if (t == 0) s_run = 0;
    __syncthreads();
    for (int base = 0; base < n; base += 1024) {
        int i = base + t;
        int v = (i < n) ? cnt[i] : 0;
        int x = v;
#pragma unroll
        for (int off = 1; off < 64; off <<= 1) {
            int y = __shfl_up(x, off);
            if (lane >= off) x += y;
        }
        if (lane == 63) wsum[wid] = x;
        __syncthreads();
        if (t == 0) {
            int a = 0;
            for (int j = 0; j < 16; ++j) { int tmp = wsum[j]; wsum[j] = a; a += tmp; }
            wsum[16] = a;
        }
        __syncthreads();
        if (i < n) rs[i] = s_run + wsum[wid] + x - v;
        __syncthreads();
        if (t == 0) s_run += wsum[16];
        __syncthreads();
    }
    if (t == 0) rs[n] = s_run;
}

__global__ void fill_kernel(const int* __restrict__ dst, const int* __restrict__ rs,
                            int* __restrict__ cursor, int* __restrict__ eid, int E)
{
    int e = blockIdx.x * 256 + threadIdx.x;
    if (e >= E) return;
    int d = dst[e];
    int p = atomicAdd(&cursor[d], 1);
    eid[rs[d] + p] = e;
}

// per-node insertion sort -> segment content ascending edge id (deterministic)
__global__ void sort_kernel(const int* __restrict__ rs, int* __restrict__ eid, int N)
{
    int n = blockIdx.x * 256 + threadIdx.x;
    if (n >= N) return;
    const int b = rs[n], len = rs[n + 1] - b;
    for (int i = 1; i < len; ++i) {
        int key = eid[b + i];
        int j = i - 1;
        while (j >= 0 && eid[b + j] > key) { eid[b + j + 1] = eid[b + j]; --j; }
        eid[b + j + 1] = key;
    }
}

// ---------------- GCN aggregate; reads bf16 xw, writes bf16 x ----------------
__global__ __launch_bounds__(256)
void gcn_kernel(const u16* __restrict__ xw, const int* __restrict__ src,
                const u8* __restrict__ keep,
                const int* __restrict__ rs, const int* __restrict__ eid,
                const float* __restrict__ dinv, const float* __restrict__ gb,
                u16* __restrict__ xout, int N)
{
    const int n = blockIdx.x;
    const int d = threadIdx.x;
    const float di = dinv[n];
    float acc = bf2f(xw[(size_t)n * 256 + d]) * di * di;
    const int e0 = rs[n], e1 = rs[n + 1];
    for (int i = e0; i < e1; ++i) {
        const int e = eid[i];
        if (!keep[e]) continue;
        const int s = src[e];
        acc = fmaf(bf2f(xw[(size_t)s * 256 + d]), dinv[s] * di, acc);
    }
    xout[(size_t)n * 256 + d] = f2bf(acc + gb[d]);
}

// ---------------- TransformerConv, one head from fused qkv [n][768] ----------------
__global__ __launch_bounds__(256)
void tconv_head_kernel(const u16* __restrict__ qkv,
                       const int* __restrict__ src, const u8* __restrict__ keep,
                       const int* __restrict__ rs, const int* __restrict__ eid,
                       float* __restrict__ xacc, int N)
{
    const int wid = threadIdx.x >> 6, lane = threadIdx.x & 63;
    const int n = blockIdx.x * 4 + wid;
    if (n >= N) return;
    const ushort4 qu = *(const ushort4*)&qkv[(size_t)n * 768 + lane * 4];
    const float q0 = bf2f(qu.x), q1 = bf2f(qu.y), q2 = bf2f(qu.z), q3 = bf2f(qu.w);
    const int e0 = rs[n], e1 = rs[n + 1];
    float m = -1e30f, den = 0.f;
    float a0 = 0.f, a1 = 0.f, a2 = 0.f, a3 = 0.f;
    for (int i = e0; i < e1; ++i) {
        const int e = eid[i];
        if (!keep[e]) continue;
        const int s = src[e];
        const ushort4 ku = *(const ushort4*)&qkv[(size_t)s * 768 + 256 + lane * 4];
        float p = q0 * bf2f(ku.x) + q1 * bf2f(ku.y) + q2 * bf2f(ku.z) + q3 * bf2f(ku.w);
        p = wave_sum(p);
        const float lg = p * (1.f / 16.f);
        if (lg > m) {
            const float sc = __expf(m - lg);
            den *= sc; a0 *= sc; a1 *= sc; a2 *= sc; a3 *= sc;
            m = lg;
        }
        const float w = __expf(lg - m);
        den += w;
        const ushort4 vu = *(const ushort4*)&qkv[(size_t)s * 768 + 512 + lane * 4];
        a0 = fmaf(w, bf2f(vu.x), a0); a1 = fmaf(w, bf2f(vu.y), a1);
        a2 = fmaf(w, bf2f(vu.z), a2); a3 = fmaf(w, bf2f(vu.w), a3);
    }
    const float inv = 0.25f / fmaxf(den, 1e-16f);
    float4* p4 = (float4*)&xacc[(size_t)n * 256 + lane * 4];
    float4 cur = *p4;
    cur.x += a0 * inv; cur.y += a1 * inv; cur.z += a2 * inv; cur.w += a3 * inv;
    *p4 = cur;
}

// ---------------- recon loss partials ----------------
__global__ __launch_bounds__(256)
void recon_kernel(const float* __restrict__ x, const u8* __restrict__ mask,
                  const float* __restrict__ aeb,
                  float* __restrict__ rblkS, float* __restrict__ rblkC, int N)
{
    const int total = N * 256;
    float s = 0.f, c = 0.f;
    for (int idx = blockIdx.x * 256 + threadIdx.x; idx < total; idx += gridDim.x * 256) {
        const int n = idx >> 8, d = idx & 255;
        if (mask[n]) {
            const float diff = aeb[d] - x[idx];
            s = fmaf(diff, diff, s);
            if (d == 0) c += 1.f;
        }
    }
    s = wave_sum(s); c = wave_sum(c);
    __shared__ float ss[4], cc[4];
    const int lane = threadIdx.x & 63, wid = threadIdx.x >> 6;
    if (lane == 0) { ss[wid] = s; cc[wid] = c; }
    __syncthreads();
    if (threadIdx.x == 0) {
        rblkS[blockIdx.x] = ss[0] + ss[1] + ss[2] + ss[3];
        rblkC[blockIdx.x] = cc[0] + cc[1] + cc[2] + cc[3];
    }
}

// ---------------- pair scores + per-block edge-pred partials ----------------
__global__ __launch_bounds__(256)
void score_kernel(const float* __restrict__ x, const int* __restrict__ user,
                  const int* __restrict__ wine,
                  const float* __restrict__ epw, const float* __restrict__ epb,
                  const float* __restrict__ fcw, const float* __restrict__ fcb,
                  float* __restrict__ out, float* __restrict__ sblk, int B)
{
    __shared__ float sep[4];
    const int wid = threadIdx.x >> 6, lane = threadIdx.x & 63;
    const int b = blockIdx.x * 4 + wid;
    if (b < B) {
        const size_t u = (size_t)user[b];
        const size_t w = (size_t)wine[b] + NU_C;
        const float4 xu = *(const float4*)&x[u * 256 + lane * 4];
        const float4 xw = *(const float4*)&x[w * 256 + lane * 4];
        const float4 e1 = *(const float4*)&epw[lane * 4];
        const float4 e2 = *(const float4*)&epw[256 + lane * 4];
        const float4 f1 = *(const float4*)&fcw[lane * 4];
        const float4 f2 = *(const float4*)&fcw[256 + lane * 4];
        float pep = xu.x * e1.x + xu.y * e1.y + xu.z * e1.z + xu.w * e1.w
                  + xw.x * e2.x + xw.y * e2.y + xw.z * e2.z + xw.w * e2.w;
        float pfc = xu.x * f1.x + xu.y * f1.y + xu.z * f1.z + xu.w * f1.w
                  + xw.x * f2.x + xw.y * f2.y + xw.z * f2.z + xw.w * f2.w;
        pep = wave_sum(pep); pfc = wave_sum(pfc);
        if (lane == 0) {
            const float es = 1.f / (1.f + __expf(-(pep + epb[0])));
            sep[wid] = (es - 1.f) * (es - 1.f);
            out[b] = 1.f / (1.f + __expf(-(pfc + fcb[0]))) * 4.f + 1.f;
        }
    } else if (lane == 0) {
        sep[wid] = 0.f;
    }
    __syncthreads();
    if (threadIdx.x == 0) sblk[blockIdx.x] = sep[0] + sep[1] + sep[2] + sep[3];
}

__global__ __launch_bounds__(1024)
void final_reduce_kernel(const float* __restrict__ rblkS, const float* __restrict__ rblkC,
                         const float* __restrict__ sblk, float* __restrict__ out, int B)
{
    const int t = threadIdx.x, lane = t & 63, wid = t >> 6;
    float s = rblkS[t] + rblkS[t + 1024];
    float c = rblkC[t] + rblkC[t + 1024];
    float p = sblk[t] + sblk[t + 1024];
    s = wave_sum(s); c = wave_sum(c); p = wave_sum(p);
    __shared__ float ss[16], cc[16], pp[16];
    if (lane == 0) { ss[wid] = s; cc[wid] = c; pp[wid] = p; }
    __syncthreads();
    if (t == 0) {
        float S = 0.f, C = 0.f, P = 0.f;
        for (int i = 0; i < 16; ++i) { S += ss[i]; C += cc[i]; P += pp[i]; }
        out[B] = S / (C * 256.f);
        out[B + 1] = P / (float)B;
    }
}

extern "C" void kernel_launch(void* const* d_in, const int* in_sizes, int n_in,
                              void* d_out, int out_size, void* d_ws, size_t ws_size,
                              hipStream_t stream)
{
    const int* user = (const int*)d_in[0];
    const int* wine = (const int*)d_in[1];
    const int* e_src = (const int*)d_in[2];
    const int* e_dst = e_src + E_C;
    const void* keep_raw  = d_in[3];
    const void* nmask_raw = d_in[4];
    const float* user_emb = (const float*)d_in[5];
    const float* wine_emb = (const float*)d_in[6];
    const float* up_w = (const float*)d_in[7];
    const float* up_b = (const float*)d_in[8];
    const float* wp_w = (const float*)d_in[9];
    const float* wp_b = (const float*)d_in[10];
    const float* sf_proj_w = (const float*)d_in[11];
    const float* sf_proj_b = (const float*)d_in[12];
    const float* sf_q_w = (const float*)d_in[13];
    const float* sf_q_b = (const float*)d_in[14];
    const float* sf_k_w = (const float*)d_in[15];
    const float* sf_k_b = (const float*)d_in[16];
    const float* sf_v_w = (const float*)d_in[17];
    const float* sf_v_b = (const float*)d_in[18];
    const float* sf_o_w = (const float*)d_in[19];
    const float* sf_o_b = (const float*)d_in[20];
    const float* sf_fc_w = (const float*)d_in[21];
    const float* sf_fc_b = (const float*)d_in[22];
    const float* g_w = (const float*)d_in[23];
    const float* g_b = (const float*)d_in[24];
    const float* t_q_w = (const float*)d_in[25];
    const float* t_q_b = (const float*)d_in[26];
    const float* t_k_w = (const float*)d_in[27];
    const float* t_k_b = (const float*)d_in[28];
    const float* t_v_w = (const float*)d_in[29];
    const float* t_v_b = (const float*)d_in[30];
    const float* t_skip_w = (const float*)d_in[31];
    const float* t_skip_b = (const float*)d_in[32];
    const float* fc_w = (const float*)d_in[33];
    const float* fc_b = (const float*)d_in[34];
    const float* ae_b = (const float*)d_in[36];
    const float* ep_w = (const float*)d_in[37];
    const float* ep_b = (const float*)d_in[38];
    const float* wsf = (const float*)d_in[39];
    float* out = (float*)d_out;
    char* ws = (char*)d_ws;

    size_t off = 0;
    auto take = [&](size_t b) { size_t r = off; off += (b + 255) & ~(size_t)255; return r; };
    const size_t o_xb     = take((size_t)N_C * 256 * 2);
    const size_t o_cnt    = take((size_t)N_C * 4);     // zero region start
    const size_t o_degw   = take((size_t)N_C * 4);
    const size_t o_cursor = take((size_t)N_C * 4);
    const size_t o_scal   = take(256);                 // flag
    const size_t o_rowst  = take((size_t)(N_C + 1) * 4);
    const size_t o_dinv   = take((size_t)N_C * 4);
    const size_t o_eid    = take((size_t)E_C * 4);
    const size_t o_kmask  = take((size_t)E_C);
    const size_t o_nmask  = take((size_t)N_C);
    const size_t o_rblkS  = take(2048 * 4);
    const size_t o_rblkC  = take(2048 * 4);
    const size_t o_sblk   = take(2048 * 4);
    const size_t o_wt     = take((size_t)WT_ELEMS * 2);
    const size_t o_bias   = take(3584 * 4);
    const size_t ARENA    = 102400000;
    const size_t o_arena  = take(ARENA);
    const size_t NEED = off;

    if (ws_size < NEED) {
        fillval_kernel<<<dim3((out_size + 255) / 256), 256, 0, stream>>>(
            out, out_size, (float)((double)ws_size / (1024.0 * 1024.0)));
        return;
    }

    u16*   xb     = (u16*)  (ws + o_xb);
    int*   cnt    = (int*)  (ws + o_cnt);
    float* degw   = (float*)(ws + o_degw);
    int*   cursor = (int*)  (ws + o_cursor);
    int*   flag   = (int*)  (ws + o_scal);
    int*   rowst  = (int*)  (ws + o_rowst);
    float* dinvb  = (float*)(ws + o_dinv);
    int*   eid    = (int*)  (ws + o_eid);
    u8*    kmask  = (u8*)   (ws + o_kmask);
    u8*    nmaskb = (u8*)   (ws + o_nmask);
    float* rblkS  = (float*)(ws + o_rblkS);
    float* rblkC  = (float*)(ws + o_rblkC);
    float* sblk   = (float*)(ws + o_sblk);
    u16*   WT     = (u16*)  (ws + o_wt);
    float* kvb    = (float*)(ws + o_bias);
    float* qkvb   = kvb + 512;

    // WT region offsets (elements)
    u16* wt_up   = WT + 0;
    u16* wt_wp   = WT + 16384;
    u16* wt_proj = WT + 32768;
    u16* wt_sfq  = WT + 49152;
    u16* wt_sfkv = WT + 114688;   // [512,256]
    u16* wt_sfo  = WT + 245760;
    u16* wt_sffc = WT + 311296;   // [256,512]
    u16* wt_g    = WT + 442368;
    u16* wt_skip = WT + 507904;
    u16* wt_qkv  = WT + 573440;   // per head h: +h*196608, [768,256]

    // arena overlays:
    u16* ue16  = (u16*)(ws + o_arena);                    //  3.84 MB
    u16* we16  = (u16*)(ws + o_arena + 3840000);          //  1.28 MB
    u16* wsf16 = (u16*)(ws + o_arena + 5120000);          //  5.12 MB
    u16* cat   = (u16*)(ws + o_arena + 10240000);         // [NI,512]
    u16* side  = (u16*)(ws + o_arena + 20480000);         // [NI*4,256]
    u16* qbuf  = (u16*)(ws + o_arena + 40960000);         // [NI,256]
    u16* kvbuf = (u16*)(ws + o_arena + 46080000);         // [NI*4,512]
    u16* aobuf = (u16*)(ws + o_arena + 87040000);         // [NI,256]
    u16* xw    = (u16*)(ws + o_arena);                    // bf16 [N,256] (phase B)
    u16* qkvh  = (u16*)(ws + o_arena);                    // [N,768] bf16 (phase C)
    float* xacc = (float*)(ws + o_arena + 61440000);      // f32 [N,256]

    const int zero_words = (3 * N_C * 4 + 256) / 4;
    zero_kernel<<<dim3((zero_words + 255) / 256), 256, 0, stream>>>((unsigned int*)cnt, zero_words);

    detect_kernel<<<dim3((E_C / 4 + 255) / 256), 256, 0, stream>>>((const unsigned int*)keep_raw, E_C / 4, flag);
    conv_mask_kernel<<<dim3((E_C + 255) / 256), 256, 0, stream>>>(keep_raw, kmask, E_C, flag);
    conv_mask_kernel<<<dim3((N_C + 255) / 256), 256, 0, stream>>>(nmask_raw, nmaskb, N_C, flag);

    // ---- prep: convert embeddings, transpose weights, fuse biases ----
    conv3_kernel<<<dim3(2048), 256, 0, stream>>>(user_emb, NU_C * 16, wine_emb, NI_C * 16,
                                                 wsf, N_C * 16, ue16, we16, wsf16);
    wtrans_kernel<<<dim3(WT_ELEMS / 256), 256, 0, stream>>>(up_w, wp_w, sf_proj_w, sf_q_w,
        sf_k_w, sf_v_w, sf_o_w, sf_fc_w, g_w, t_skip_w, t_q_w, t_k_w, t_v_w, WT);
    prep_bias_kernel<<<dim3(12), 256, 0, stream>>>(sf_k_b, sf_v_b, t_q_b, t_k_b, t_v_b, kvb, qkvb);

    // ---- phase A ----
    mgemm_kernel<u16><<<dim3(2, 118), 512, 0, stream>>>(ue16, 64, wt_up, up_b, xb, 256, NU_C, 256, 64);
    mgemm_kernel<u16><<<dim3(2, 40), 512, 0, stream>>>(we16, 64, wt_wp, wp_b, cat, 512, NI_C, 256, 64);
    mgemm_kernel<u16><<<dim3(2, 157), 512, 0, stream>>>(wsf16, 64, wt_proj, sf_proj_b, side, 256, N_C, 256, 64);
    mgemm_kernel<u16><<<dim3(2, 40), 512, 0, stream>>>(cat, 512, wt_sfq, sf_q_b, qbuf, 256, NI_C, 256, 256);
    mgemm_kernel<u16><<<dim3(4, 157), 512, 0, stream>>>(side, 256, wt_sfkv, kvb, kvbuf, 512, N_C, 512, 256);
    side_attn_kernel<<<dim3(2500), 256, 0, stream>>>(qbuf, kvbuf, aobuf, NI_C);
    mgemm_kernel<u16><<<dim3(2, 40), 512, 0, stream>>>(aobuf, 256, wt_sfo, sf_o_b, cat + 256, 512, NI_C, 256, 256);
    mgemm_kernel<u16><<<dim3(2, 40), 512, 0, stream>>>(cat, 512, wt_sffc, sf_fc_b, xb + (size_t)NU_C * 256, 256, NI_C, 256, 512);

    // ---- deterministic CSR (atomic fill + per-node sort) ----
    degw_kernel<<<dim3((E_C + 255) / 256), 256, 0, stream>>>(e_dst, kmask, degw, E_C);
    dinv_kernel<<<dim3((N_C + 255) / 256), 256, 0, stream>>>(degw, dinvb, N_C);
    count_kernel<<<dim3((E_C + 255) / 256), 256, 0, stream>>>(e_dst, cnt, E_C);
    scan_kernel<<<dim3(1), 1024, 0, stream>>>(cnt, rowst, N_C);
    fill_kernel<<<dim3((E_C + 255) / 256), 256, 0, stream>>>(e_dst, rowst, cursor, eid, E_C);
    sort_kernel<<<dim3((N_C + 255) / 256), 256, 0, stream>>>(rowst, eid, N_C);

    // ---- phase B: GCN ----
    mgemm_kernel<u16><<<dim3(2, 157), 512, 0, stream>>>(xb, 256, wt_g, nullptr, xw, 256, N_C, 256, 256);
    gcn_kernel<<<dim3(N_C), 256, 0, stream>>>(xw, e_src, kmask, rowst, eid, dinvb, g_b, xb, N_C);

    // ---- phase C: skip + per-head fused QKV + tconv ----
    mgemm_kernel<float><<<dim3(2, 157), 512, 0, stream>>>(xb, 256, wt_skip, t_skip_b, xacc, 256, N_C, 256, 256);
    for (int h = 0; h < 4; ++h) {
        mgemm_kernel<u16><<<dim3(6, 157), 512, 0, stream>>>(xb, 256, wt_qkv + h * 196608,
                                                            qkvb + h * 768, qkvh, 768, N_C, 768, 256);
        tconv_head_kernel<<<dim3(N_C / 4), 256, 0, stream>>>(qkvh, e_src, kmask, rowst, eid, xacc, N_C);
    }

    // ---- losses + scores ----
    recon_kernel<<<dim3(2048), 256, 0, stream>>>(xacc, nmaskb, ae_b, rblkS, rblkC, N_C);
    score_kernel<<<dim3(2048), 256, 0, stream>>>(xacc, user, wine, ep_w, ep_b, fc_w, fc_b, out, sblk, B_C);
    final_reduce_kernel<<<dim3(1), 1024, 0, stream>>>(rblkS, rblkC, sblk, out, B_C);
}

// Round 10
// 615.829 us; speedup vs baseline: 1.3102x; 1.1367x over previous
//
#include <hip/hip_runtime.h>
#include <stdint.h>

typedef unsigned short u16;
typedef unsigned char u8;
typedef __attribute__((ext_vector_type(8))) short bf16x8;
typedef __attribute__((ext_vector_type(4))) float f32x4;

#define NU_C 30000
#define NI_C 10000
#define N_C  40000
#define E_C  100000
#define B_C  8192

static __device__ __forceinline__ float bf2f(u16 u) {
    union { unsigned int i; float f; } c; c.i = ((unsigned int)u) << 16; return c.f;
}
static __device__ __forceinline__ u16 f2bf(float f) {
    union { float f; unsigned int i; } c; c.f = f;
    return (u16)((c.i + 0x7FFFu + ((c.i >> 16) & 1u)) >> 16);
}
static __device__ __forceinline__ float wave_sum(float v) {
#pragma unroll
    for (int off = 32; off > 0; off >>= 1) v += __shfl_xor(v, off);
    return v;
}

__global__ void zero_kernel(unsigned int* p, int n) {
    int i = blockIdx.x * 256 + threadIdx.x;
    if (i < n) p[i] = 0u;
}
__global__ void fillval_kernel(float* p, int n, float v) {
    int i = blockIdx.x * 256 + threadIdx.x;
    if (i < n) p[i] = v;
}

// ---- bool-layout detection ----
__global__ void detect_kernel(const unsigned int* a, int n, int* flag) {
    int i = blockIdx.x * 256 + threadIdx.x;
    if (i >= n) return;
    unsigned int v = a[i];
    int f = 0;
    if (v > 1u) f |= 1;
    if (v != 0u && v != 0x3F800000u) f |= 2;
    if (f) atomicOr(flag, f);
}
__global__ void conv_masks_kernel(const void* keep_raw, const void* nm_raw,
                                  u8* km, u8* nm, int E, int N, const int* flag)
{
    int i = blockIdx.x * 256 + threadIdx.x;
    const int f = *flag;
    if (i < E) {
        u8 r;
        if ((f & 1) == 0)      r = ((const int*)keep_raw)[i] != 0;
        else if ((f & 2) == 0) r = ((const float*)keep_raw)[i] != 0.f;
        else                   r = ((const u8*)keep_raw)[i] != 0;
        km[i] = r;
    }
    int j = i - E;
    if (j >= 0 && j < N) {
        u8 r;
        if ((f & 1) == 0)      r = ((const int*)nm_raw)[j] != 0;
        else if ((f & 2) == 0) r = ((const float*)nm_raw)[j] != 0.f;
        else                   r = ((const u8*)nm_raw)[j] != 0;
        nm[j] = r;
    }
}

// ---- f32 -> bf16 conversion for the three embedding inputs ----
__global__ void conv3_kernel(const float* __restrict__ a, int na4,
                             const float* __restrict__ b, int nb4,
                             const float* __restrict__ c, int nc4,
                             u16* __restrict__ oa, u16* __restrict__ ob, u16* __restrict__ oc)
{
    int tot = na4 + nb4 + nc4;
    for (int i = blockIdx.x * 256 + threadIdx.x; i < tot; i += gridDim.x * 256) {
        const float* s; u16* o; int j = i;
        if (j < na4) { s = a; o = oa; }
        else if ((j -= na4) < nb4) { s = b; o = ob; }
        else { j -= nb4; s = c; o = oc; }
        float4 v = *(const float4*)&s[(size_t)j * 4];
        ushort4 r;
        r.x = f2bf(v.x); r.y = f2bf(v.y); r.z = f2bf(v.z); r.w = f2bf(v.w);
        *(ushort4*)&o[(size_t)j * 4] = r;
    }
}

// ---- batched weight transpose+convert: WT[n*K + k] = bf16(W[k*ldw + coloff + n]) ----
#define WT_ELEMS 1359872
__device__ const int wd_prefix[23] = {0,16384,32768,49152,114688,180224,245760,311296,442368,
    507904,573440,638976,704512,770048,835584,901120,966656,1032192,1097728,1163264,1228800,
    1294336,1359872};
__device__ const u8  wd_src[22]  = {0,1,2,3,4,5,6,7,8,9,10,11,12,10,11,12,10,11,12,10,11,12};
__device__ const short wd_ldw[22]= {256,256,256,256,256,256,256,256,256,256,
    1024,1024,1024,1024,1024,1024,1024,1024,1024,1024,1024,1024};
__device__ const short wd_coff[22]={0,0,0,0,0,0,0,0,0,0, 0,0,0, 256,256,256, 512,512,512, 768,768,768};
__device__ const short wd_kmask[22]={63,63,63,255,255,255,255,511,255,255,
    255,255,255,255,255,255,255,255,255,255,255,255};
__device__ const u8  wd_ksh[22] = {6,6,6,8,8,8,8,9,8,8, 8,8,8,8,8,8,8,8,8,8,8,8};

__global__ __launch_bounds__(256)
void wtrans_kernel(const float* w0, const float* w1, const float* w2, const float* w3,
                   const float* w4, const float* w5, const float* w6, const float* w7,
                   const float* w8, const float* w9, const float* w10, const float* w11,
                   const float* w12, u16* __restrict__ WT)
{
    int idx = blockIdx.x * 256 + threadIdx.x;
    if (idx >= WT_ELEMS) return;
    int d = 0;
    while (wd_prefix[d + 1] <= idx) ++d;
    const int local = idx - wd_prefix[d];
    const int k = local & wd_kmask[d];
    const int n = local >> wd_ksh[d];
    const float* s;
    switch (wd_src[d]) {
        case 0: s = w0; break; case 1: s = w1; break; case 2: s = w2; break;
        case 3: s = w3; break; case 4: s = w4; break; case 5: s = w5; break;
        case 6: s = w6; break; case 7: s = w7; break; case 8: s = w8; break;
        case 9: s = w9; break; case 10: s = w10; break; case 11: s = w11; break;
        default: s = w12; break;
    }
    WT[idx] = f2bf(s[(size_t)k * wd_ldw[d] + wd_coff[d] + n]);
}

// ---- fused bias vectors ----
__global__ void prep_bias_kernel(const float* sfk_b, const float* sfv_b,
                                 const float* tq_b, const float* tk_b, const float* tv_b,
                                 float* kvb, float* qkvb)
{
    int i = blockIdx.x * 256 + threadIdx.x;
    if (i < 512) kvb[i] = i < 256 ? sfk_b[i] : sfv_b[i - 256];
    if (i < 3072) {
        int h = i / 768, j = i - h * 768;
        qkvb[i] = j < 256 ? tq_b[h * 256 + j]
                : (j < 512 ? tk_b[h * 256 + j - 256] : tv_b[h * 256 + j - 512]);
    }
}

// ---------------- MFMA bf16 GEMM: C[M,N] = A[M,K] @ WT^T (+bias) ----------------
// 256x128 tile, BK=64, 8 waves 4x2; XCD-bijective block swizzle (R9-validated).
template <typename OT>
__global__ __launch_bounds__(512)
void mgemm_kernel(const u16* __restrict__ A, int lda,
                  const u16* __restrict__ WT,
                  const float* __restrict__ bias,
                  OT* __restrict__ C, int ldc,
                  int M, int N, int K)
{
    __shared__ __align__(16) u16 As[256][72];
    __shared__ __align__(16) u16 Bs[128][72];
    const int t = threadIdx.x;
    const int wid = t >> 6, lane = t & 63;
    const int wr = wid >> 1, wc = wid & 1;
    const int lr = lane & 15, lg = lane >> 4;
    const int gx = gridDim.x;
    const int nwg = gx * gridDim.y;
    const int orig = blockIdx.y * gx + blockIdx.x;
    const int q8 = nwg >> 3, r8 = nwg & 7;
    const int xcd = orig & 7, oidx = orig >> 3;
    const int swzb = (xcd < r8 ? xcd * (q8 + 1) : r8 * (q8 + 1) + (xcd - r8) * q8) + oidx;
    const int row0 = (swzb / gx) * 256, col0 = (swzb % gx) * 128;
    const int sra = t >> 1, sha = (t & 1) * 32;
    const int srb = t >> 2, shb = (t & 3) * 16;
    f32x4 acc[4][4] = {};

    for (int k0 = 0; k0 < K; k0 += 64) {
        {
            const int gr = row0 + sra;
            if (gr < M) {
                const u16* ap = &A[(size_t)gr * lda + k0 + sha];
#pragma unroll
                for (int j = 0; j < 4; ++j)
                    *(bf16x8*)&As[sra][sha + j * 8] = *(const bf16x8*)&ap[j * 8];
            } else {
                const bf16x8 z = {0, 0, 0, 0, 0, 0, 0, 0};
#pragma unroll
                for (int j = 0; j < 4; ++j)
                    *(bf16x8*)&As[sra][sha + j * 8] = z;
            }
        }
        {
            const u16* bp = &WT[(size_t)(col0 + srb) * K + k0 + shb];
#pragma unroll
            for (int j = 0; j < 2; ++j)
                *(bf16x8*)&Bs[srb][shb + j * 8] = *(const bf16x8*)&bp[j * 8];
        }
        __syncthreads();
#pragma unroll
        for (int kk = 0; kk < 2; ++kk) {
            bf16x8 af[4], bfr[4];
#pragma unroll
            for (int m = 0; m < 4; ++m)
                af[m] = *(const bf16x8*)&As[wr * 64 + m * 16 + lr][kk * 32 + lg * 8];
#pragma unroll
            for (int n = 0; n < 4; ++n)
                bfr[n] = *(const bf16x8*)&Bs[wc * 64 + n * 16 + lr][kk * 32 + lg * 8];
#pragma unroll
            for (int m = 0; m < 4; ++m)
#pragma unroll
                for (int n = 0; n < 4; ++n)
                    acc[m][n] = __builtin_amdgcn_mfma_f32_16x16x32_bf16(af[m], bfr[n], acc[m][n], 0, 0, 0);
        }
        __syncthreads();
    }
#pragma unroll
    for (int m = 0; m < 4; ++m) {
#pragma unroll
        for (int r = 0; r < 4; ++r) {
            int row = row0 + wr * 64 + m * 16 + lg * 4 + r;
            if (row >= M) continue;
#pragma unroll
            for (int n = 0; n < 4; ++n) {
                int col = col0 + wc * 64 + n * 16 + lr;
                float v = acc[m][n][r];
                if (bias) v += bias[col];
                if constexpr (sizeof(OT) == 4) C[(size_t)row * ldc + col] = v;
                else C[(size_t)row * ldc + col] = f2bf(v);
            }
        }
    }
}

// ---------------- side fusion attention ----------------
__global__ __launch_bounds__(256)
void side_attn_kernel(const u16* __restrict__ q, const u16* __restrict__ kv,
                      u16* __restrict__ ao, int NI)
{
    const int wid = threadIdx.x >> 6, lane = threadIdx.x & 63;
    const int n = blockIdx.x * 4 + wid;
    if (n >= NI) return;
    const ushort4 qu = *(const ushort4*)&q[(size_t)n * 256 + lane * 4];
    const float q0 = bf2f(qu.x), q1 = bf2f(qu.y), q2 = bf2f(qu.z), q3 = bf2f(qu.w);
    float logit[4];
#pragma unroll
    for (int tk = 0; tk < 4; ++tk) {
        const ushort4 ku = *(const ushort4*)&kv[((size_t)n * 4 + tk) * 512 + lane * 4];
        float p = q0 * bf2f(ku.x) + q1 * bf2f(ku.y) + q2 * bf2f(ku.z) + q3 * bf2f(ku.w);
        logit[tk] = wave_sum(p) * (1.f / 16.f);
    }
    float mx = fmaxf(fmaxf(logit[0], logit[1]), fmaxf(logit[2], logit[3]));
    float e[4], den = 0.f;
#pragma unroll
    for (int tk = 0; tk < 4; ++tk) { e[tk] = __expf(logit[tk] - mx); den += e[tk]; }
    const float inv = 1.f / den;
    float o0 = 0.f, o1 = 0.f, o2 = 0.f, o3 = 0.f;
#pragma unroll
    for (int tk = 0; tk < 4; ++tk) {
        const ushort4 vu = *(const ushort4*)&kv[((size_t)n * 4 + tk) * 512 + 256 + lane * 4];
        const float w = e[tk] * inv;
        o0 = fmaf(w, bf2f(vu.x), o0); o1 = fmaf(w, bf2f(vu.y), o1);
        o2 = fmaf(w, bf2f(vu.z), o2); o3 = fmaf(w, bf2f(vu.w), o3);
    }
    ushort4 o;
    o.x = f2bf(o0); o.y = f2bf(o1); o.z = f2bf(o2); o.w = f2bf(o3);
    *(ushort4*)&ao[(size_t)n * 256 + lane * 4] = o;
}

// ---------------- deterministic CSR build ----------------
__global__ void count_kernel(const int* __restrict__ dst, const u8* __restrict__ keep,
                             int* __restrict__ cnt, float* __restrict__ degw, int E)
{
    int e = blockIdx.x * 256 + threadIdx.x;
    if (e >= E) return;
    int d = dst[e];
    atomicAdd(&cnt[d], 1);
    if (keep[e]) atomicAdd(&degw[d], 1.f);
}

__global__ void dinv_kernel(const float* __restrict__ degw, float* __restrict__ dinv, int N)
{
    int n = blockIdx.x * 256 + threadIdx.x;
    if (n < N) dinv[n] = rsqrtf(degw[n] + 1.f);
}

__global__ __launch_bounds__(1024)
void scan_kernel(const int* __restrict__ cnt, int* __restrict__ rs, int n)
{
    __shared__ int wsum[17];
    __shared__ int s_run;
    const int t = threadIdx.x, lane = t & 63, wid = t >> 6;
    if (t == 0) s_run = 0;
    __syncthreads();
    for (int base = 0; base < n; base += 1024) {
        int i = base + t;
        int v = (i < n) ? cnt[i] : 0;
        int x = v;
#pragma unroll
        for (int off = 1; off < 64; off <<= 1) {
            int y = __shfl_up(x, off);
            if (lane >= off) x += y;
        }
        if (lane == 63) wsum[wid] = x;
        __syncthreads();
        if (t == 0) {
            int a = 0;
            for (int j = 0; j < 16; ++j) { int tmp = wsum[j]; wsum[j] = a; a += tmp; }
            wsum[16] = a;
        }
        __syncthreads();
        if (i < n) rs[i] = s_run + wsum[wid] + x - v;
        __syncthreads();
        if (t == 0) s_run += wsum[16];
        __syncthreads();
    }
    if (t == 0) rs[n] = s_run;
}

__global__ void fill_kernel(const int* __restrict__ dst, const int* __restrict__ rs,
                            int* __restrict__ cursor, int* __restrict__ eid, int E)
{
    int e = blockIdx.x * 256 + threadIdx.x;
    if (e >= E) return;
    int d = dst[e];
    int p = atomicAdd(&cursor[d], 1);
    eid[rs[d] + p] = e;
}

__global__ void sort_kernel(const int* __restrict__ rs, int* __restrict__ eid, int N)
{
    int n = blockIdx.x * 256 + threadIdx.x;
    if (n >= N) return;
    const int b = rs[n], len = rs[n + 1] - b;
    for (int i = 1; i < len; ++i) {
        int key = eid[b + i];
        int j = i - 1;
        while (j >= 0 && eid[b + j] > key) { eid[b + j + 1] = eid[b + j]; --j; }
        eid[b + j + 1] = key;
    }
}

// per-edge flattened arrays: ssrc[i]=src*2+keep ; wnorm[i]=keep? dinv[src]*dinv[dst] : 0
__global__ void edge_prep_kernel(const int* __restrict__ eid, const int* __restrict__ src,
                                 const int* __restrict__ dst, const u8* __restrict__ keep,
                                 const float* __restrict__ dinv,
                                 int* __restrict__ ssrc, float* __restrict__ wnorm, int E)
{
    int i = blockIdx.x * 256 + threadIdx.x;
    if (i >= E) return;
    const int e = eid[i];
    const int s = src[e];
    const u8 k = keep[e];
    ssrc[i] = s * 2 + (int)k;
    wnorm[i] = k ? dinv[s] * dinv[dst[e]] : 0.f;
}

// ---------------- GCN aggregate: one wave per node, ushort4/lane ----------------
__global__ __launch_bounds__(256)
void gcn_kernel(const u16* __restrict__ xw, const int* __restrict__ ssrc,
                const float* __restrict__ wnorm, const int* __restrict__ rs,
                const float* __restrict__ dinv, const float* __restrict__ gb,
                u16* __restrict__ xout, int N)
{
    const int wid = threadIdx.x >> 6, lane = threadIdx.x & 63;
    const int n = blockIdx.x * 4 + wid;
    if (n >= N) return;
    const float di = dinv[n];
    const float dii = di * di;
    const ushort4 own = *(const ushort4*)&xw[(size_t)n * 256 + lane * 4];
    float a0 = bf2f(own.x) * dii, a1 = bf2f(own.y) * dii;
    float a2 = bf2f(own.z) * dii, a3 = bf2f(own.w) * dii;
    const int e0 = rs[n], e1 = rs[n + 1];
    for (int i = e0; i < e1; ++i) {
        const float w = wnorm[i];
        const int s = ssrc[i] >> 1;
        const ushort4 r = *(const ushort4*)&xw[(size_t)s * 256 + lane * 4];
        a0 = fmaf(bf2f(r.x), w, a0); a1 = fmaf(bf2f(r.y), w, a1);
        a2 = fmaf(bf2f(r.z), w, a2); a3 = fmaf(bf2f(r.w), w, a3);
    }
    const float4 g = *(const float4*)&gb[lane * 4];
    ushort4 o;
    o.x = f2bf(a0 + g.x); o.y = f2bf(a1 + g.y);
    o.z = f2bf(a2 + g.z); o.w = f2bf(a3 + g.w);
    *(ushort4*)&xout[(size_t)n * 256 + lane * 4] = o;
}

// ---------------- TransformerConv head: branchless online softmax, 2-edge unroll ----------------
__global__ __launch_bounds__(256)
void tconv_head_kernel(const u16* __restrict__ qkv, const int* __restrict__ ssrc,
                       const int* __restrict__ rs, float* __restrict__ xacc, int N)
{
    const int wid = threadIdx.x >> 6, lane = threadIdx.x & 63;
    const int n = blockIdx.x * 4 + wid;
    if (n >= N) return;
    const ushort4 qu = *(const ushort4*)&qkv[(size_t)n * 768 + lane * 4];
    const float q0 = bf2f(qu.x), q1 = bf2f(qu.y), q2 = bf2f(qu.z), q3 = bf2f(qu.w);
    const int e0 = rs[n], e1 = rs[n + 1];
    float m = -1e30f, den = 0.f;
    float a0 = 0.f, a1 = 0.f, a2 = 0.f, a3 = 0.f;
    int i = e0;
    for (; i + 1 < e1; i += 2) {
        const int va = ssrc[i], vb = ssrc[i + 1];
        const int sa = va >> 1, sb = vb >> 1;
        const float ewa = (float)(va & 1), ewb = (float)(vb & 1);
        const ushort4 ka = *(const ushort4*)&qkv[(size_t)sa * 768 + 256 + lane * 4];
        const ushort4 kb = *(const ushort4*)&qkv[(size_t)sb * 768 + 256 + lane * 4];
        const ushort4 xa = *(const ushort4*)&qkv[(size_t)sa * 768 + 512 + lane * 4];
        const ushort4 xb4 = *(const ushort4*)&qkv[(size_t)sb * 768 + 512 + lane * 4];
        float pa = q0 * bf2f(ka.x) + q1 * bf2f(ka.y) + q2 * bf2f(ka.z) + q3 * bf2f(ka.w);
        float pb = q0 * bf2f(kb.x) + q1 * bf2f(kb.y) + q2 * bf2f(kb.z) + q3 * bf2f(kb.w);
        pa = wave_sum(pa) * (1.f / 16.f);
        pb = wave_sum(pb) * (1.f / 16.f);
        {
            const float mn = fmaxf(m, pa);
            const float sc = __expf(m - mn);
            const float w = __expf(pa - mn) * ewa;
            den = den * sc + w;
            a0 = fmaf(w, bf2f(xa.x), a0 * sc); a1 = fmaf(w, bf2f(xa.y), a1 * sc);
            a2 = fmaf(w, bf2f(xa.z), a2 * sc); a3 = fmaf(w, bf2f(xa.w), a3 * sc);
            m = mn;
        }
        {
            const float mn = fmaxf(m, pb);
            const float sc = __expf(m - mn);
            const float w = __expf(pb - mn) * ewb;
            den = den * sc + w;
            a0 = fmaf(w, bf2f(xb4.x), a0 * sc); a1 = fmaf(w, bf2f(xb4.y), a1 * sc);
            a2 = fmaf(w, bf2f(xb4.z), a2 * sc); a3 = fmaf(w, bf2f(xb4.w), a3 * sc);
            m = mn;
        }
    }
    if (i < e1) {
        const int va = ssrc[i];
        const int sa = va >> 1;
        const float ewa = (float)(va & 1);
        const ushort4 ka = *(const ushort4*)&qkv[(size_t)sa * 768 + 256 + lane * 4];
        const ushort4 xa = *(const ushort4*)&qkv[(size_t)sa * 768 + 512 + lane * 4];
        float pa = q0 * bf2f(ka.x) + q1 * bf2f(ka.y) + q2 * bf2f(ka.z) + q3 * bf2f(ka.w);
        pa = wave_sum(pa) * (1.f / 16.f);
        const float mn = fmaxf(m, pa);
        const float sc = __expf(m - mn);
        const float w = __expf(pa - mn) * ewa;
        den = den * sc + w;
        a0 = fmaf(w, bf2f(xa.x), a0 * sc); a1 = fmaf(w, bf2f(xa.y), a1 * sc);
        a2 = fmaf(w, bf2f(xa.z), a2 * sc); a3 = fmaf(w, bf2f(xa.w), a3 * sc);
    }
    const float inv = 0.25f / fmaxf(den, 1e-16f);
    float4* p4 = (float4*)&xacc[(size_t)n * 256 + lane * 4];
    float4 cur = *p4;
    cur.x += a0 * inv; cur.y += a1 * inv; cur.z += a2 * inv; cur.w += a3 * inv;
    *p4 = cur;
}

// ---------------- recon loss partials ----------------
__global__ __launch_bounds__(256)
void recon_kernel(const float* __restrict__ x, const u8* __restrict__ mask,
                  const float* __restrict__ aeb,
                  float* __restrict__ rblkS, float* __restrict__ rblkC, int N)
{
    const int total = N * 256;
    float s = 0.f, c = 0.f;
    for (int idx = blockIdx.x * 256 + threadIdx.x; idx < total; idx += gridDim.x * 256) {
        const int n = idx >> 8, d = idx & 255;
        if (mask[n]) {
            const float diff = aeb[d] - x[idx];
            s = fmaf(diff, diff, s);
            if (d == 0) c += 1.f;
        }
    }
    s = wave_sum(s); c = wave_sum(c);
    __shared__ float ss[4], cc[4];
    const int lane = threadIdx.x & 63, wid = threadIdx.x >> 6;
    if (lane == 0) { ss[wid] = s; cc[wid] = c; }
    __syncthreads();
    if (threadIdx.x == 0) {
        rblkS[blockIdx.x] = ss[0] + ss[1] + ss[2] + ss[3];
        rblkC[blockIdx.x] = cc[0] + cc[1] + cc[2] + cc[3];
    }
}

// ---------------- pair scores + per-block edge-pred partials ----------------
__global__ __launch_bounds__(256)
void score_kernel(const float* __restrict__ x, const int* __restrict__ user,
                  const int* __restrict__ wine,
                  const float* __restrict__ epw, const float* __restrict__ epb,
                  const float* __restrict__ fcw, const float* __restrict__ fcb,
                  float* __restrict__ out, float* __restrict__ sblk, int B)
{
    __shared__ float sep[4];
    const int wid = threadIdx.x >> 6, lane = threadIdx.x & 63;
    const int b = blockIdx.x * 4 + wid;
    if (b < B) {
        const size_t u = (size_t)user[b];
        const size_t w = (size_t)wine[b] + NU_C;
        const float4 xu = *(const float4*)&x[u * 256 + lane * 4];
        const float4 xw = *(const float4*)&x[w * 256 + lane * 4];
        const float4 e1 = *(const float4*)&epw[lane * 4];
        const float4 e2 = *(const float4*)&epw[256 + lane * 4];
        const float4 f1 = *(const float4*)&fcw[lane * 4];
        const float4 f2 = *(const float4*)&fcw[256 + lane * 4];
        float pep = xu.x * e1.x + xu.y * e1.y + xu.z * e1.z + xu.w * e1.w
                  + xw.x * e2.x + xw.y * e2.y + xw.z * e2.z + xw.w * e2.w;
        float pfc = xu.x * f1.x + xu.y * f1.y + xu.z * f1.z + xu.w * f1.w
                  + xw.x * f2.x + xw.y * f2.y + xw.z * f2.z + xw.w * f2.w;
        pep = wave_sum(pep); pfc = wave_sum(pfc);
        if (lane == 0) {
            const float es = 1.f / (1.f + __expf(-(pep + epb[0])));
            sep[wid] = (es - 1.f) * (es - 1.f);
            out[b] = 1.f / (1.f + __expf(-(pfc + fcb[0]))) * 4.f + 1.f;
        }
    } else if (lane == 0) {
        sep[wid] = 0.f;
    }
    __syncthreads();
    if (threadIdx.x == 0) sblk[blockIdx.x] = sep[0] + sep[1] + sep[2] + sep[3];
}

__global__ __launch_bounds__(1024)
void final_reduce_kernel(const float* __restrict__ rblkS, const float* __restrict__ rblkC,
                         const float* __restrict__ sblk, float* __restrict__ out, int B)
{
    const int t = threadIdx.x, lane = t & 63, wid = t >> 6;
    float s = rblkS[t] + rblkS[t + 1024];
    float c = rblkC[t] + rblkC[t + 1024];
    float p = sblk[t] + sblk[t + 1024];
    s = wave_sum(s); c = wave_sum(c); p = wave_sum(p);
    __shared__ float ss[16], cc[16], pp[16];
    if (lane == 0) { ss[wid] = s; cc[wid] = c; pp[wid] = p; }
    __syncthreads();
    if (t == 0) {
        float S = 0.f, C = 0.f, P = 0.f;
        for (int i = 0; i < 16; ++i) { S += ss[i]; C += cc[i]; P += pp[i]; }
        out[B] = S / (C * 256.f);
        out[B + 1] = P / (float)B;
    }
}

extern "C" void kernel_launch(void* const* d_in, const int* in_sizes, int n_in,
                              void* d_out, int out_size, void* d_ws, size_t ws_size,
                              hipStream_t stream)
{
    const int* user = (const int*)d_in[0];
    const int* wine = (const int*)d_in[1];
    const int* e_src = (const int*)d_in[2];
    const int* e_dst = e_src + E_C;
    const void* keep_raw  = d_in[3];
    const void* nmask_raw = d_in[4];
    const float* user_emb = (const float*)d_in[5];
    const float* wine_emb = (const float*)d_in[6];
    const float* up_w = (const float*)d_in[7];
    const float* up_b = (const float*)d_in[8];
    const float* wp_w = (const float*)d_in[9];
    const float* wp_b = (const float*)d_in[10];
    const float* sf_proj_w = (const float*)d_in[11];
    const float* sf_proj_b = (const float*)d_in[12];
    const float* sf_q_w = (const float*)d_in[13];
    const float* sf_q_b = (const float*)d_in[14];
    const float* sf_k_w = (const float*)d_in[15];
    const float* sf_k_b = (const float*)d_in[16];
    const float* sf_v_w = (const float*)d_in[17];
    const float* sf_v_b = (const float*)d_in[18];
    const float* sf_o_w = (const float*)d_in[19];
    const float* sf_o_b = (const float*)d_in[20];
    const float* sf_fc_w = (const float*)d_in[21];
    const float* sf_fc_b = (const float*)d_in[22];
    const float* g_w = (const float*)d_in[23];
    const float* g_b = (const float*)d_in[24];
    const float* t_q_w = (const float*)d_in[25];
    const float* t_q_b = (const float*)d_in[26];
    const float* t_k_w = (const float*)d_in[27];
    const float* t_k_b = (const float*)d_in[28];
    const float* t_v_w = (const float*)d_in[29];
    const float* t_v_b = (const float*)d_in[30];
    const float* t_skip_w = (const float*)d_in[31];
    const float* t_skip_b = (const float*)d_in[32];
    const float* fc_w = (const float*)d_in[33];
    const float* fc_b = (const float*)d_in[34];
    const float* ae_b = (const float*)d_in[36];
    const float* ep_w = (const float*)d_in[37];
    const float* ep_b = (const float*)d_in[38];
    const float* wsf = (const float*)d_in[39];
    float* out = (float*)d_out;
    char* ws = (char*)d_ws;

    size_t off = 0;
    auto take = [&](size_t b) { size_t r = off; off += (b + 255) & ~(size_t)255; return r; };
    const size_t o_xb     = take((size_t)N_C * 256 * 2);
    const size_t o_cnt    = take((size_t)N_C * 4);     // zero region start
    const size_t o_degw   = take((size_t)N_C * 4);
    const size_t o_cursor = take((size_t)N_C * 4);
    const size_t o_scal   = take(256);                 // flag
    const size_t o_rowst  = take((size_t)(N_C + 1) * 4);
    const size_t o_dinv   = take((size_t)N_C * 4);
    const size_t o_eid    = take((size_t)E_C * 4);
    const size_t o_ssrc   = take((size_t)E_C * 4);
    const size_t o_wnorm  = take((size_t)E_C * 4);
    const size_t o_kmask  = take((size_t)E_C);
    const size_t o_nmask  = take((size_t)N_C);
    const size_t o_rblkS  = take(2048 * 4);
    const size_t o_rblkC  = take(2048 * 4);
    const size_t o_sblk   = take(2048 * 4);
    const size_t o_wt     = take((size_t)WT_ELEMS * 2);
    const size_t o_bias   = take(3584 * 4);
    const size_t ARENA    = 102400000;
    const size_t o_arena  = take(ARENA);
    const size_t NEED = off;

    if (ws_size < NEED) {
        fillval_kernel<<<dim3((out_size + 255) / 256), 256, 0, stream>>>(
            out, out_size, (float)((double)ws_size / (1024.0 * 1024.0)));
        return;
    }

    u16*   xb     = (u16*)  (ws + o_xb);
    int*   cnt    = (int*)  (ws + o_cnt);
    float* degw   = (float*)(ws + o_degw);
    int*   cursor = (int*)  (ws + o_cursor);
    int*   flag   = (int*)  (ws + o_scal);
    int*   rowst  = (int*)  (ws + o_rowst);
    float* dinvb  = (float*)(ws + o_dinv);
    int*   eid    = (int*)  (ws + o_eid);
    int*   ssrc   = (int*)  (ws + o_ssrc);
    float* wnorm  = (float*)(ws + o_wnorm);
    u8*    kmask  = (u8*)   (ws + o_kmask);
    u8*    nmaskb = (u8*)   (ws + o_nmask);
    float* rblkS  = (float*)(ws + o_rblkS);
    float* rblkC  = (float*)(ws + o_rblkC);
    float* sblk   = (float*)(ws + o_sblk);
    u16*   WT     = (u16*)  (ws + o_wt);
    float* kvb    = (float*)(ws + o_bias);
    float* qkvb   = kvb + 512;

    // WT region offsets (elements)
    u16* wt_up   = WT + 0;
    u16* wt_wp   = WT + 16384;
    u16* wt_proj = WT + 32768;
    u16* wt_sfq  = WT + 49152;
    u16* wt_sfkv = WT + 114688;   // [512,256]
    u16* wt_sfo  = WT + 245760;
    u16* wt_sffc = WT + 311296;   // [256,512]
    u16* wt_g    = WT + 442368;
    u16* wt_skip = WT + 507904;
    u16* wt_qkv  = WT + 573440;   // per head h: +h*196608, [768,256]

    // arena overlays:
    u16* ue16  = (u16*)(ws + o_arena);
    u16* we16  = (u16*)(ws + o_arena + 3840000);
    u16* wsf16 = (u16*)(ws + o_arena + 5120000);
    u16* cat   = (u16*)(ws + o_arena + 10240000);
    u16* side  = (u16*)(ws + o_arena + 20480000);
    u16* qbuf  = (u16*)(ws + o_arena + 40960000);
    u16* kvbuf = (u16*)(ws + o_arena + 46080000);
    u16* aobuf = (u16*)(ws + o_arena + 87040000);
    u16* xw    = (u16*)(ws + o_arena);                    // bf16 [N,256] (phase B)
    u16* qkvh  = (u16*)(ws + o_arena);                    // [N,768] bf16 (phase C)
    float* xacc = (float*)(ws + o_arena + 61440000);      // f32 [N,256]

    const int zero_words = (3 * N_C * 4 + 256) / 4;
    zero_kernel<<<dim3((zero_words + 255) / 256), 256, 0, stream>>>((unsigned int*)cnt, zero_words);

    detect_kernel<<<dim3((E_C / 4 + 255) / 256), 256, 0, stream>>>((const unsigned int*)keep_raw, E_C / 4, flag);
    conv_masks_kernel<<<dim3((E_C + N_C + 255) / 256), 256, 0, stream>>>(keep_raw, nmask_raw, kmask, nmaskb, E_C, N_C, flag);

    // ---- prep: convert embeddings, transpose weights, fuse biases ----
    conv3_kernel<<<dim3(2048), 256, 0, stream>>>(user_emb, NU_C * 16, wine_emb, NI_C * 16,
                                                 wsf, N_C * 16, ue16, we16, wsf16);
    wtrans_kernel<<<dim3(WT_ELEMS / 256), 256, 0, stream>>>(up_w, wp_w, sf_proj_w, sf_q_w,
        sf_k_w, sf_v_w, sf_o_w, sf_fc_w, g_w, t_skip_w, t_q_w, t_k_w, t_v_w, WT);
    prep_bias_kernel<<<dim3(12), 256, 0, stream>>>(sf_k_b, sf_v_b, t_q_b, t_k_b, t_v_b, kvb, qkvb);

    // ---- phase A ----
    mgemm_kernel<u16><<<dim3(2, 118), 512, 0, stream>>>(ue16, 64, wt_up, up_b, xb, 256, NU_C, 256, 64);
    mgemm_kernel<u16><<<dim3(2, 40), 512, 0, stream>>>(we16, 64, wt_wp, wp_b, cat, 512, NI_C, 256, 64);
    mgemm_kernel<u16><<<dim3(2, 157), 512, 0, stream>>>(wsf16, 64, wt_proj, sf_proj_b, side, 256, N_C, 256, 64);
    mgemm_kernel<u16><<<dim3(2, 40), 512, 0, stream>>>(cat, 512, wt_sfq, sf_q_b, qbuf, 256, NI_C, 256, 256);
    mgemm_kernel<u16><<<dim3(4, 157), 512, 0, stream>>>(side, 256, wt_sfkv, kvb, kvbuf, 512, N_C, 512, 256);
    side_attn_kernel<<<dim3(2500), 256, 0, stream>>>(qbuf, kvbuf, aobuf, NI_C);
    mgemm_kernel<u16><<<dim3(2, 40), 512, 0, stream>>>(aobuf, 256, wt_sfo, sf_o_b, cat + 256, 512, NI_C, 256, 256);
    mgemm_kernel<u16><<<dim3(2, 40), 512, 0, stream>>>(cat, 512, wt_sffc, sf_fc_b, xb + (size_t)NU_C * 256, 256, NI_C, 256, 512);

    // ---- deterministic CSR (count+degw fused; atomic fill + per-node sort; edge flatten) ----
    count_kernel<<<dim3((E_C + 255) / 256), 256, 0, stream>>>(e_dst, kmask, cnt, degw, E_C);
    dinv_kernel<<<dim3((N_C + 255) / 256), 256, 0, stream>>>(degw, dinvb, N_C);
    scan_kernel<<<dim3(1), 1024, 0, stream>>>(cnt, rowst, N_C);
    fill_kernel<<<dim3((E_C + 255) / 256), 256, 0, stream>>>(e_dst, rowst, cursor, eid, E_C);
    sort_kernel<<<dim3((N_C + 255) / 256), 256, 0, stream>>>(rowst, eid, N_C);
    edge_prep_kernel<<<dim3((E_C + 255) / 256), 256, 0, stream>>>(eid, e_src, e_dst, kmask, dinvb, ssrc, wnorm, E_C);

    // ---- phase B: GCN ----
    mgemm_kernel<u16><<<dim3(2, 157), 512, 0, stream>>>(xb, 256, wt_g, nullptr, xw, 256, N_C, 256, 256);
    gcn_kernel<<<dim3(N_C / 4), 256, 0, stream>>>(xw, ssrc, wnorm, rowst, dinvb, g_b, xb, N_C);

    // ---- phase C: skip + per-head fused QKV + tconv ----
    mgemm_kernel<float><<<dim3(2, 157), 512, 0, stream>>>(xb, 256, wt_skip, t_skip_b, xacc, 256, N_C, 256, 256);
    for (int h = 0; h < 4; ++h) {
        mgemm_kernel<u16><<<dim3(6, 157), 512, 0, stream>>>(xb, 256, wt_qkv + h * 196608,
                                                            qkvb + h * 768, qkvh, 768, N_C, 768, 256);
        tconv_head_kernel<<<dim3(N_C / 4), 256, 0, stream>>>(qkvh, ssrc, rowst, xacc, N_C);
    }

    // ---- losses + scores ----
    recon_kernel<<<dim3(2048), 256, 0, stream>>>(xacc, nmaskb, ae_b, rblkS, rblkC, N_C);
    score_kernel<<<dim3(2048), 256, 0, stream>>>(xacc, user, wine, ep_w, ep_b, fc_w, fc_b, out, sblk, B_C);
    final_reduce_kernel<<<dim3(1), 1024, 0, stream>>>(rblkS, rblkC, sblk, out, B_C);
}

// Round 11
// 604.515 us; speedup vs baseline: 1.3347x; 1.0187x over previous
//
#include <hip/hip_runtime.h>
#include <stdint.h>

typedef unsigned short u16;
typedef unsigned char u8;
typedef __attribute__((ext_vector_type(8))) short bf16x8;
typedef __attribute__((ext_vector_type(4))) float f32x4;

#define NU_C 30000
#define NI_C 10000
#define N_C  40000
#define E_C  100000
#define B_C  8192

static __device__ __forceinline__ float bf2f(u16 u) {
    union { unsigned int i; float f; } c; c.i = ((unsigned int)u) << 16; return c.f;
}
static __device__ __forceinline__ u16 f2bf(float f) {
    union { float f; unsigned int i; } c; c.f = f;
    return (u16)((c.i + 0x7FFFu + ((c.i >> 16) & 1u)) >> 16);
}
static __device__ __forceinline__ float wave_sum(float v) {
#pragma unroll
    for (int off = 32; off > 0; off >>= 1) v += __shfl_xor(v, off);
    return v;
}

__global__ void zero_kernel(unsigned int* p, int n) {
    int i = blockIdx.x * 256 + threadIdx.x;
    if (i < n) p[i] = 0u;
}
__global__ void fillval_kernel(float* p, int n, float v) {
    int i = blockIdx.x * 256 + threadIdx.x;
    if (i < n) p[i] = v;
}

// ---- bool-layout detection ----
__global__ void detect_kernel(const unsigned int* a, int n, int* flag) {
    int i = blockIdx.x * 256 + threadIdx.x;
    if (i >= n) return;
    unsigned int v = a[i];
    int f = 0;
    if (v > 1u) f |= 1;
    if (v != 0u && v != 0x3F800000u) f |= 2;
    if (f) atomicOr(flag, f);
}
__global__ void conv_masks_kernel(const void* keep_raw, const void* nm_raw,
                                  u8* km, u8* nm, int E, int N, const int* flag)
{
    int i = blockIdx.x * 256 + threadIdx.x;
    const int f = *flag;
    if (i < E) {
        u8 r;
        if ((f & 1) == 0)      r = ((const int*)keep_raw)[i] != 0;
        else if ((f & 2) == 0) r = ((const float*)keep_raw)[i] != 0.f;
        else                   r = ((const u8*)keep_raw)[i] != 0;
        km[i] = r;
    }
    int j = i - E;
    if (j >= 0 && j < N) {
        u8 r;
        if ((f & 1) == 0)      r = ((const int*)nm_raw)[j] != 0;
        else if ((f & 2) == 0) r = ((const float*)nm_raw)[j] != 0.f;
        else                   r = ((const u8*)nm_raw)[j] != 0;
        nm[j] = r;
    }
}

// ---- f32 -> bf16 conversion for the three embedding inputs ----
__global__ void conv3_kernel(const float* __restrict__ a, int na4,
                             const float* __restrict__ b, int nb4,
                             const float* __restrict__ c, int nc4,
                             u16* __restrict__ oa, u16* __restrict__ ob, u16* __restrict__ oc)
{
    int tot = na4 + nb4 + nc4;
    for (int i = blockIdx.x * 256 + threadIdx.x; i < tot; i += gridDim.x * 256) {
        const float* s; u16* o; int j = i;
        if (j < na4) { s = a; o = oa; }
        else if ((j -= na4) < nb4) { s = b; o = ob; }
        else { j -= nb4; s = c; o = oc; }
        float4 v = *(const float4*)&s[(size_t)j * 4];
        ushort4 r;
        r.x = f2bf(v.x); r.y = f2bf(v.y); r.z = f2bf(v.z); r.w = f2bf(v.w);
        *(ushort4*)&o[(size_t)j * 4] = r;
    }
}

// ---- batched weight transpose+convert: WT[n*K + k] = bf16(W[k*ldw + coloff + n]) ----
#define WT_ELEMS 1359872
__device__ const int wd_prefix[23] = {0,16384,32768,49152,114688,180224,245760,311296,442368,
    507904,573440,638976,704512,770048,835584,901120,966656,1032192,1097728,1163264,1228800,
    1294336,1359872};
__device__ const u8  wd_src[22]  = {0,1,2,3,4,5,6,7,8,9,10,11,12,10,11,12,10,11,12,10,11,12};
__device__ const short wd_ldw[22]= {256,256,256,256,256,256,256,256,256,256,
    1024,1024,1024,1024,1024,1024,1024,1024,1024,1024,1024,1024};
__device__ const short wd_coff[22]={0,0,0,0,0,0,0,0,0,0, 0,0,0, 256,256,256, 512,512,512, 768,768,768};
__device__ const short wd_kmask[22]={63,63,63,255,255,255,255,511,255,255,
    255,255,255,255,255,255,255,255,255,255,255,255};
__device__ const u8  wd_ksh[22] = {6,6,6,8,8,8,8,9,8,8, 8,8,8,8,8,8,8,8,8,8,8,8};

__global__ __launch_bounds__(256)
void wtrans_kernel(const float* w0, const float* w1, const float* w2, const float* w3,
                   const float* w4, const float* w5, const float* w6, const float* w7,
                   const float* w8, const float* w9, const float* w10, const float* w11,
                   const float* w12, u16* __restrict__ WT)
{
    int idx = blockIdx.x * 256 + threadIdx.x;
    if (idx >= WT_ELEMS) return;
    int d = 0;
    while (wd_prefix[d + 1] <= idx) ++d;
    const int local = idx - wd_prefix[d];
    const int k = local & wd_kmask[d];
    const int n = local >> wd_ksh[d];
    const float* s;
    switch (wd_src[d]) {
        case 0: s = w0; break; case 1: s = w1; break; case 2: s = w2; break;
        case 3: s = w3; break; case 4: s = w4; break; case 5: s = w5; break;
        case 6: s = w6; break; case 7: s = w7; break; case 8: s = w8; break;
        case 9: s = w9; break; case 10: s = w10; break; case 11: s = w11; break;
        default: s = w12; break;
    }
    WT[idx] = f2bf(s[(size_t)k * wd_ldw[d] + wd_coff[d] + n]);
}

// ---- fused bias vectors ----
__global__ void prep_bias_kernel(const float* sfk_b, const float* sfv_b,
                                 const float* tq_b, const float* tk_b, const float* tv_b,
                                 float* kvb, float* qkvb)
{
    int i = blockIdx.x * 256 + threadIdx.x;
    if (i < 512) kvb[i] = i < 256 ? sfk_b[i] : sfv_b[i - 256];
    if (i < 3072) {
        int h = i / 768, j = i - h * 768;
        qkvb[i] = j < 256 ? tq_b[h * 256 + j]
                : (j < 512 ? tk_b[h * 256 + j - 256] : tv_b[h * 256 + j - 512]);
    }
}

// ---------------- MFMA bf16 GEMM: C[M,N] = A[M,K] @ WT^T (+bias) ----------------
// 256x128 tile, BK=64, 8 waves 4x2; XCD-bijective block swizzle (R9/R10-validated)
// + T14 reg-prefetch: tile k+1 global loads issue before tile k's MFMA.
// LDS-bound at 2 blocks/CU (55 KB), so +24 VGPR does not change occupancy.
template <typename OT>
__global__ __launch_bounds__(512)
void mgemm_kernel(const u16* __restrict__ A, int lda,
                  const u16* __restrict__ WT,
                  const float* __restrict__ bias,
                  OT* __restrict__ C, int ldc,
                  int M, int N, int K)
{
    __shared__ __align__(16) u16 As[256][72];
    __shared__ __align__(16) u16 Bs[128][72];
    const int t = threadIdx.x;
    const int wid = t >> 6, lane = t & 63;
    const int wr = wid >> 1, wc = wid & 1;
    const int lr = lane & 15, lg = lane >> 4;
    const int gx = gridDim.x;
    const int nwg = gx * gridDim.y;
    const int orig = blockIdx.y * gx + blockIdx.x;
    const int q8 = nwg >> 3, r8 = nwg & 7;
    const int xcd = orig & 7, oidx = orig >> 3;
    const int swzb = (xcd < r8 ? xcd * (q8 + 1) : r8 * (q8 + 1) + (xcd - r8) * q8) + oidx;
    const int row0 = (swzb / gx) * 256, col0 = (swzb % gx) * 128;
    const int sra = t >> 1, sha = (t & 1) * 32;
    const int srb = t >> 2, shb = (t & 3) * 16;
    const bool avalid = (row0 + sra) < M;
    const u16* aptr = &A[(size_t)min(row0 + sra, M - 1) * lda];
    const u16* bptr = &WT[(size_t)(col0 + srb) * K];
    const bf16x8 z = {0, 0, 0, 0, 0, 0, 0, 0};
    f32x4 acc[4][4] = {};
    bf16x8 ra[4], rb[2];

    auto gload = [&](int k0) {
#pragma unroll
        for (int j = 0; j < 4; ++j)
            ra[j] = avalid ? *(const bf16x8*)&aptr[k0 + sha + j * 8] : z;
#pragma unroll
        for (int j = 0; j < 2; ++j)
            rb[j] = *(const bf16x8*)&bptr[k0 + shb + j * 8];
    };
    auto swrite = [&]() {
#pragma unroll
        for (int j = 0; j < 4; ++j)
            *(bf16x8*)&As[sra][sha + j * 8] = ra[j];
#pragma unroll
        for (int j = 0; j < 2; ++j)
            *(bf16x8*)&Bs[srb][shb + j * 8] = rb[j];
    };
    auto compute = [&]() {
#pragma unroll
        for (int kk = 0; kk < 2; ++kk) {
            bf16x8 af[4], bfr[4];
#pragma unroll
            for (int m = 0; m < 4; ++m)
                af[m] = *(const bf16x8*)&As[wr * 64 + m * 16 + lr][kk * 32 + lg * 8];
#pragma unroll
            for (int n = 0; n < 4; ++n)
                bfr[n] = *(const bf16x8*)&Bs[wc * 64 + n * 16 + lr][kk * 32 + lg * 8];
#pragma unroll
            for (int m = 0; m < 4; ++m)
#pragma unroll
                for (int n = 0; n < 4; ++n)
                    acc[m][n] = __builtin_amdgcn_mfma_f32_16x16x32_bf16(af[m], bfr[n], acc[m][n], 0, 0, 0);
        }
    };

    gload(0);
    swrite();
    __syncthreads();
    for (int k0 = 64; k0 < K; k0 += 64) {
        gload(k0);          // issue next-tile loads; latency hides under compute()
        compute();          // consume current LDS tile
        __syncthreads();    // all reads of current tile done
        swrite();           // write prefetched tile (vmcnt waits drained during MFMA)
        __syncthreads();
    }
    compute();

#pragma unroll
    for (int m = 0; m < 4; ++m) {
#pragma unroll
        for (int r = 0; r < 4; ++r) {
            int row = row0 + wr * 64 + m * 16 + lg * 4 + r;
            if (row >= M) continue;
#pragma unroll
            for (int n = 0; n < 4; ++n) {
                int col = col0 + wc * 64 + n * 16 + lr;
                float v = acc[m][n][r];
                if (bias) v += bias[col];
                if constexpr (sizeof(OT) == 4) C[(size_t)row * ldc + col] = v;
                else C[(size_t)row * ldc + col] = f2bf(v);
            }
        }
    }
}

// ---------------- side fusion attention ----------------
__global__ __launch_bounds__(256)
void side_attn_kernel(const u16* __restrict__ q, const u16* __restrict__ kv,
                      u16* __restrict__ ao, int NI)
{
    const int wid = threadIdx.x >> 6, lane = threadIdx.x & 63;
    const int n = blockIdx.x * 4 + wid;
    if (n >= NI) return;
    const ushort4 qu = *(const ushort4*)&q[(size_t)n * 256 + lane * 4];
    const float q0 = bf2f(qu.x), q1 = bf2f(qu.y), q2 = bf2f(qu.z), q3 = bf2f(qu.w);
    float logit[4];
#pragma unroll
    for (int tk = 0; tk < 4; ++tk) {
        const ushort4 ku = *(const ushort4*)&kv[((size_t)n * 4 + tk) * 512 + lane * 4];
        float p = q0 * bf2f(ku.x) + q1 * bf2f(ku.y) + q2 * bf2f(ku.z) + q3 * bf2f(ku.w);
        logit[tk] = wave_sum(p) * (1.f / 16.f);
    }
    float mx = fmaxf(fmaxf(logit[0], logit[1]), fmaxf(logit[2], logit[3]));
    float e[4], den = 0.f;
#pragma unroll
    for (int tk = 0; tk < 4; ++tk) { e[tk] = __expf(logit[tk] - mx); den += e[tk]; }
    const float inv = 1.f / den;
    float o0 = 0.f, o1 = 0.f, o2 = 0.f, o3 = 0.f;
#pragma unroll
    for (int tk = 0; tk < 4; ++tk) {
        const ushort4 vu = *(const ushort4*)&kv[((size_t)n * 4 + tk) * 512 + 256 + lane * 4];
        const float w = e[tk] * inv;
        o0 = fmaf(w, bf2f(vu.x), o0); o1 = fmaf(w, bf2f(vu.y), o1);
        o2 = fmaf(w, bf2f(vu.z), o2); o3 = fmaf(w, bf2f(vu.w), o3);
    }
    ushort4 o;
    o.x = f2bf(o0); o.y = f2bf(o1); o.z = f2bf(o2); o.w = f2bf(o3);
    *(ushort4*)&ao[(size_t)n * 256 + lane * 4] = o;
}

// ---------------- deterministic CSR build ----------------
__global__ void count_kernel(const int* __restrict__ dst, const u8* __restrict__ keep,
                             int* __restrict__ cnt, float* __restrict__ degw, int E)
{
    int e = blockIdx.x * 256 + threadIdx.x;
    if (e >= E) return;
    int d = dst[e];
    atomicAdd(&cnt[d], 1);
    if (keep[e]) atomicAdd(&degw[d], 1.f);
}

__global__ void dinv_kernel(const float* __restrict__ degw, float* __restrict__ dinv, int N)
{
    int n = blockIdx.x * 256 + threadIdx.x;
    if (n < N) dinv[n] = rsqrtf(degw[n] + 1.f);
}

__global__ __launch_bounds__(1024)
void scan_kernel(const int* __restrict__ cnt, int* __restrict__ rs, int n)
{
    __shared__ int wsum[17];
    __shared__ int s_run;
    const int t = threadIdx.x, lane = t & 63, wid = t >> 6;
    if (t == 0) s_run = 0;
    __syncthreads();
    for (int base = 0; base < n; base += 1024) {
        int i = base + t;
        int v = (i < n) ? cnt[i] : 0;
        int x = v;
#pragma unroll
        for (int off = 1; off < 64; off <<= 1) {
            int y = __shfl_up(x, off);
            if (lane >= off) x += y;
        }
        if (lane == 63) wsum[wid] = x;
        __syncthreads();
        if (t == 0) {
            int a = 0;
            for (int j = 0; j < 16; ++j) { int tmp = wsum[j]; wsum[j] = a; a += tmp; }
            wsum[16] = a;
        }
        __syncthreads();
        if (i < n) rs[i] = s_run + wsum[wid] + x - v;
        __syncthreads();
        if (t == 0) s_run += wsum[16];
        __syncthreads();
    }
    if (t == 0) rs[n] = s_run;
}

__global__ void fill_kernel(const int* __restrict__ dst, const int* __restrict__ rs,
                            int* __restrict__ cursor, int* __restrict__ eid, int E)
{
    int e = blockIdx.x * 256 + threadIdx.x;
    if (e >= E) return;
    int d = dst[e];
    int p = atomicAdd(&cursor[d], 1);
    eid[rs[d] + p] = e;
}

__global__ void sort_kernel(const int* __restrict__ rs, int* __restrict__ eid, int N)
{
    int n = blockIdx.x * 256 + threadIdx.x;
    if (n >= N) return;
    const int b = rs[n], len = rs[n + 1] - b;
    for (int i = 1; i < len; ++i) {
        int key = eid[b + i];
        int j = i - 1;
        while (j >= 0 && eid[b + j] > key) { eid[b + j + 1] = eid[b + j]; --j; }
        eid[b + j + 1] = key;
    }
}

// per-edge flattened arrays: ssrc[i]=src*2+keep ; wnorm[i]=keep? dinv[src]*dinv[dst] : 0
__global__ void edge_prep_kernel(const int* __restrict__ eid, const int* __restrict__ src,
                                 const int* __restrict__ dst, const u8* __restrict__ keep,
                                 const float* __restrict__ dinv,
                                 int* __restrict__ ssrc, float* __restrict__ wnorm, int E)
{
    int i = blockIdx.x * 256 + threadIdx.x;
    if (i >= E) return;
    const int e = eid[i];
    const int s = src[e];
    const u8 k = keep[e];
    ssrc[i] = s * 2 + (int)k;
    wnorm[i] = k ? dinv[s] * dinv[dst[e]] : 0.f;
}

// ---------------- GCN aggregate: one wave per node, ushort4/lane ----------------
__global__ __launch_bounds__(256)
void gcn_kernel(const u16* __restrict__ xw, const int* __restrict__ ssrc,
                const float* __restrict__ wnorm, const int* __restrict__ rs,
                const float* __restrict__ dinv, const float* __restrict__ gb,
                u16* __restrict__ xout, int N)
{
    const int wid = threadIdx.x >> 6, lane = threadIdx.x & 63;
    const int n = blockIdx.x * 4 + wid;
    if (n >= N) return;
    const float di = dinv[n];
    const float dii = di * di;
    const ushort4 own = *(const ushort4*)&xw[(size_t)n * 256 + lane * 4];
    float a0 = bf2f(own.x) * dii, a1 = bf2f(own.y) * dii;
    float a2 = bf2f(own.z) * dii, a3 = bf2f(own.w) * dii;
    const int e0 = rs[n], e1 = rs[n + 1];
    for (int i = e0; i < e1; ++i) {
        const float w = wnorm[i];
        const int s = ssrc[i] >> 1;
        const ushort4 r = *(const ushort4*)&xw[(size_t)s * 256 + lane * 4];
        a0 = fmaf(bf2f(r.x), w, a0); a1 = fmaf(bf2f(r.y), w, a1);
        a2 = fmaf(bf2f(r.z), w, a2); a3 = fmaf(bf2f(r.w), w, a3);
    }
    const float4 g = *(const float4*)&gb[lane * 4];
    ushort4 o;
    o.x = f2bf(a0 + g.x); o.y = f2bf(a1 + g.y);
    o.z = f2bf(a2 + g.z); o.w = f2bf(a3 + g.w);
    *(ushort4*)&xout[(size_t)n * 256 + lane * 4] = o;
}

// ---------------- TransformerConv head: branchless online softmax, 2-edge unroll ----------------
__global__ __launch_bounds__(256)
void tconv_head_kernel(const u16* __restrict__ qkv, const int* __restrict__ ssrc,
                       const int* __restrict__ rs, float* __restrict__ xacc, int N)
{
    const int wid = threadIdx.x >> 6, lane = threadIdx.x & 63;
    const int n = blockIdx.x * 4 + wid;
    if (n >= N) return;
    const ushort4 qu = *(const ushort4*)&qkv[(size_t)n * 768 + lane * 4];
    const float q0 = bf2f(qu.x), q1 = bf2f(qu.y), q2 = bf2f(qu.z), q3 = bf2f(qu.w);
    const int e0 = rs[n], e1 = rs[n + 1];
    float m = -1e30f, den = 0.f;
    float a0 = 0.f, a1 = 0.f, a2 = 0.f, a3 = 0.f;
    int i = e0;
    for (; i + 1 < e1; i += 2) {
        const int va = ssrc[i], vb = ssrc[i + 1];
        const int sa = va >> 1, sb = vb >> 1;
        const float ewa = (float)(va & 1), ewb = (float)(vb & 1);
        const ushort4 ka = *(const ushort4*)&qkv[(size_t)sa * 768 + 256 + lane * 4];
        const ushort4 kb = *(const ushort4*)&qkv[(size_t)sb * 768 + 256 + lane * 4];
        const ushort4 xa = *(const ushort4*)&qkv[(size_t)sa * 768 + 512 + lane * 4];
        const ushort4 xb4 = *(const ushort4*)&qkv[(size_t)sb * 768 + 512 + lane * 4];
        float pa = q0 * bf2f(ka.x) + q1 * bf2f(ka.y) + q2 * bf2f(ka.z) + q3 * bf2f(ka.w);
        float pb = q0 * bf2f(kb.x) + q1 * bf2f(kb.y) + q2 * bf2f(kb.z) + q3 * bf2f(kb.w);
        pa = wave_sum(pa) * (1.f / 16.f);
        pb = wave_sum(pb) * (1.f / 16.f);
        {
            const float mn = fmaxf(m, pa);
            const float sc = __expf(m - mn);
            const float w = __expf(pa - mn) * ewa;
            den = den * sc + w;
            a0 = fmaf(w, bf2f(xa.x), a0 * sc); a1 = fmaf(w, bf2f(xa.y), a1 * sc);
            a2 = fmaf(w, bf2f(xa.z), a2 * sc); a3 = fmaf(w, bf2f(xa.w), a3 * sc);
            m = mn;
        }
        {
            const float mn = fmaxf(m, pb);
            const float sc = __expf(m - mn);
            const float w = __expf(pb - mn) * ewb;
            den = den * sc + w;
            a0 = fmaf(w, bf2f(xb4.x), a0 * sc); a1 = fmaf(w, bf2f(xb4.y), a1 * sc);
            a2 = fmaf(w, bf2f(xb4.z), a2 * sc); a3 = fmaf(w, bf2f(xb4.w), a3 * sc);
            m = mn;
        }
    }
    if (i < e1) {
        const int va = ssrc[i];
        const int sa = va >> 1;
        const float ewa = (float)(va & 1);
        const ushort4 ka = *(const ushort4*)&qkv[(size_t)sa * 768 + 256 + lane * 4];
        const ushort4 xa = *(const ushort4*)&qkv[(size_t)sa * 768 + 512 + lane * 4];
        float pa = q0 * bf2f(ka.x) + q1 * bf2f(ka.y) + q2 * bf2f(ka.z) + q3 * bf2f(ka.w);
        pa = wave_sum(pa) * (1.f / 16.f);
        const float mn = fmaxf(m, pa);
        const float sc = __expf(m - mn);
        const float w = __expf(pa - mn) * ewa;
        den = den * sc + w;
        a0 = fmaf(w, bf2f(xa.x), a0 * sc); a1 = fmaf(w, bf2f(xa.y), a1 * sc);
        a2 = fmaf(w, bf2f(xa.z), a2 * sc); a3 = fmaf(w, bf2f(xa.w), a3 * sc);
    }
    const float inv = 0.25f / fmaxf(den, 1e-16f);
    float4* p4 = (float4*)&xacc[(size_t)n * 256 + lane * 4];
    float4 cur = *p4;
    cur.x += a0 * inv; cur.y += a1 * inv; cur.z += a2 * inv; cur.w += a3 * inv;
    *p4 = cur;
}

// ---------------- recon loss partials ----------------
__global__ __launch_bounds__(256)
void recon_kernel(const float* __restrict__ x, const u8* __restrict__ mask,
                  const float* __restrict__ aeb,
                  float* __restrict__ rblkS, float* __restrict__ rblkC, int N)
{
    const int total = N * 256;
    float s = 0.f, c = 0.f;
    for (int idx = blockIdx.x * 256 + threadIdx.x; idx < total; idx += gridDim.x * 256) {
        const int n = idx >> 8, d = idx & 255;
        if (mask[n]) {
            const float diff = aeb[d] - x[idx];
            s = fmaf(diff, diff, s);
            if (d == 0) c += 1.f;
        }
    }
    s = wave_sum(s); c = wave_sum(c);
    __shared__ float ss[4], cc[4];
    const int lane = threadIdx.x & 63, wid = threadIdx.x >> 6;
    if (lane == 0) { ss[wid] = s; cc[wid] = c; }
    __syncthreads();
    if (threadIdx.x == 0) {
        rblkS[blockIdx.x] = ss[0] + ss[1] + ss[2] + ss[3];
        rblkC[blockIdx.x] = cc[0] + cc[1] + cc[2] + cc[3];
    }
}

// ---------------- pair scores + per-block edge-pred partials ----------------
__global__ __launch_bounds__(256)
void score_kernel(const float* __restrict__ x, const int* __restrict__ user,
                  const int* __restrict__ wine,
                  const float* __restrict__ epw, const float* __restrict__ epb,
                  const float* __restrict__ fcw, const float* __restrict__ fcb,
                  float* __restrict__ out, float* __restrict__ sblk, int B)
{
    __shared__ float sep[4];
    const int wid = threadIdx.x >> 6, lane = threadIdx.x & 63;
    const int b = blockIdx.x * 4 + wid;
    if (b < B) {
        const size_t u = (size_t)user[b];
        const size_t w = (size_t)wine[b] + NU_C;
        const float4 xu = *(const float4*)&x[u * 256 + lane * 4];
        const float4 xw = *(const float4*)&x[w * 256 + lane * 4];
        const float4 e1 = *(const float4*)&epw[lane * 4];
        const float4 e2 = *(const float4*)&epw[256 + lane * 4];
        const float4 f1 = *(const float4*)&fcw[lane * 4];
        const float4 f2 = *(const float4*)&fcw[256 + lane * 4];
        float pep = xu.x * e1.x + xu.y * e1.y + xu.z * e1.z + xu.w * e1.w
                  + xw.x * e2.x + xw.y * e2.y + xw.z * e2.z + xw.w * e2.w;
        float pfc = xu.x * f1.x + xu.y * f1.y + xu.z * f1.z + xu.w * f1.w
                  + xw.x * f2.x + xw.y * f2.y + xw.z * f2.z + xw.w * f2.w;
        pep = wave_sum(pep); pfc = wave_sum(pfc);
        if (lane == 0) {
            const float es = 1.f / (1.f + __expf(-(pep + epb[0])));
            sep[wid] = (es - 1.f) * (es - 1.f);
            out[b] = 1.f / (1.f + __expf(-(pfc + fcb[0]))) * 4.f + 1.f;
        }
    } else if (lane == 0) {
        sep[wid] = 0.f;
    }
    __syncthreads();
    if (threadIdx.x == 0) sblk[blockIdx.x] = sep[0] + sep[1] + sep[2] + sep[3];
}

__global__ __launch_bounds__(1024)
void final_reduce_kernel(const float* __restrict__ rblkS, const float* __restrict__ rblkC,
                         const float* __restrict__ sblk, float* __restrict__ out, int B)
{
    const int t = threadIdx.x, lane = t & 63, wid = t >> 6;
    float s = rblkS[t] + rblkS[t + 1024];
    float c = rblkC[t] + rblkC[t + 1024];
    float p = sblk[t] + sblk[t + 1024];
    s = wave_sum(s); c = wave_sum(c); p = wave_sum(p);
    __shared__ float ss[16], cc[16], pp[16];
    if (lane == 0) { ss[wid] = s; cc[wid] = c; pp[wid] = p; }
    __syncthreads();
    if (t == 0) {
        float S = 0.f, C = 0.f, P = 0.f;
        for (int i = 0; i < 16; ++i) { S += ss[i]; C += cc[i]; P += pp[i]; }
        out[B] = S / (C * 256.f);
        out[B + 1] = P / (float)B;
    }
}

extern "C" void kernel_launch(void* const* d_in, const int* in_sizes, int n_in,
                              void* d_out, int out_size, void* d_ws, size_t ws_size,
                              hipStream_t stream)
{
    const int* user = (const int*)d_in[0];
    const int* wine = (const int*)d_in[1];
    const int* e_src = (const int*)d_in[2];
    const int* e_dst = e_src + E_C;
    const void* keep_raw  = d_in[3];
    const void* nmask_raw = d_in[4];
    const float* user_emb = (const float*)d_in[5];
    const float* wine_emb = (const float*)d_in[6];
    const float* up_w = (const float*)d_in[7];
    const float* up_b = (const float*)d_in[8];
    const float* wp_w = (const float*)d_in[9];
    const float* wp_b = (const float*)d_in[10];
    const float* sf_proj_w = (const float*)d_in[11];
    const float* sf_proj_b = (const float*)d_in[12];
    const float* sf_q_w = (const float*)d_in[13];
    const float* sf_q_b = (const float*)d_in[14];
    const float* sf_k_w = (const float*)d_in[15];
    const float* sf_k_b = (const float*)d_in[16];
    const float* sf_v_w = (const float*)d_in[17];
    const float* sf_v_b = (const float*)d_in[18];
    const float* sf_o_w = (const float*)d_in[19];
    const float* sf_o_b = (const float*)d_in[20];
    const float* sf_fc_w = (const float*)d_in[21];
    const float* sf_fc_b = (const float*)d_in[22];
    const float* g_w = (const float*)d_in[23];
    const float* g_b = (const float*)d_in[24];
    const float* t_q_w = (const float*)d_in[25];
    const float* t_q_b = (const float*)d_in[26];
    const float* t_k_w = (const float*)d_in[27];
    const float* t_k_b = (const float*)d_in[28];
    const float* t_v_w = (const float*)d_in[29];
    const float* t_v_b = (const float*)d_in[30];
    const float* t_skip_w = (const float*)d_in[31];
    const float* t_skip_b = (const float*)d_in[32];
    const float* fc_w = (const float*)d_in[33];
    const float* fc_b = (const float*)d_in[34];
    const float* ae_b = (const float*)d_in[36];
    const float* ep_w = (const float*)d_in[37];
    const float* ep_b = (const float*)d_in[38];
    const float* wsf = (const float*)d_in[39];
    float* out = (float*)d_out;
    char* ws = (char*)d_ws;

    size_t off = 0;
    auto take = [&](size_t b) { size_t r = off; off += (b + 255) & ~(size_t)255; return r; };
    const size_t o_xb     = take((size_t)N_C * 256 * 2);
    const size_t o_cnt    = take((size_t)N_C * 4);     // zero region start
    const size_t o_degw   = take((size_t)N_C * 4);
    const size_t o_cursor = take((size_t)N_C * 4);
    const size_t o_scal   = take(256);                 // flag
    const size_t o_rowst  = take((size_t)(N_C + 1) * 4);
    const size_t o_dinv   = take((size_t)N_C * 4);
    const size_t o_eid    = take((size_t)E_C * 4);
    const size_t o_ssrc   = take((size_t)E_C * 4);
    const size_t o_wnorm  = take((size_t)E_C * 4);
    const size_t o_kmask  = take((size_t)E_C);
    const size_t o_nmask  = take((size_t)N_C);
    const size_t o_rblkS  = take(2048 * 4);
    const size_t o_rblkC  = take(2048 * 4);
    const size_t o_sblk   = take(2048 * 4);
    const size_t o_wt     = take((size_t)WT_ELEMS * 2);
    const size_t o_bias   = take(3584 * 4);
    const size_t ARENA    = 102400000;
    const size_t o_arena  = take(ARENA);
    const size_t NEED = off;

    if (ws_size < NEED) {
        fillval_kernel<<<dim3((out_size + 255) / 256), 256, 0, stream>>>(
            out, out_size, (float)((double)ws_size / (1024.0 * 1024.0)));
        return;
    }

    u16*   xb     = (u16*)  (ws + o_xb);
    int*   cnt    = (int*)  (ws + o_cnt);
    float* degw   = (float*)(ws + o_degw);
    int*   cursor = (int*)  (ws + o_cursor);
    int*   flag   = (int*)  (ws + o_scal);
    int*   rowst  = (int*)  (ws + o_rowst);
    float* dinvb  = (float*)(ws + o_dinv);
    int*   eid    = (int*)  (ws + o_eid);
    int*   ssrc   = (int*)  (ws + o_ssrc);
    float* wnorm  = (float*)(ws + o_wnorm);
    u8*    kmask  = (u8*)   (ws + o_kmask);
    u8*    nmaskb = (u8*)   (ws + o_nmask);
    float* rblkS  = (float*)(ws + o_rblkS);
    float* rblkC  = (float*)(ws + o_rblkC);
    float* sblk   = (float*)(ws + o_sblk);
    u16*   WT     = (u16*)  (ws + o_wt);
    float* kvb    = (float*)(ws + o_bias);
    float* qkvb   = kvb + 512;

    // WT region offsets (elements)
    u16* wt_up   = WT + 0;
    u16* wt_wp   = WT + 16384;
    u16* wt_proj = WT + 32768;
    u16* wt_sfq  = WT + 49152;
    u16* wt_sfkv = WT + 114688;   // [512,256]
    u16* wt_sfo  = WT + 245760;
    u16* wt_sffc = WT + 311296;   // [256,512]
    u16* wt_g    = WT + 442368;
    u16* wt_skip = WT + 507904;
    u16* wt_qkv  = WT + 573440;   // per head h: +h*196608, [768,256]

    // arena overlays:
    u16* ue16  = (u16*)(ws + o_arena);
    u16* we16  = (u16*)(ws + o_arena + 3840000);
    u16* wsf16 = (u16*)(ws + o_arena + 5120000);
    u16* cat   = (u16*)(ws + o_arena + 10240000);
    u16* side  = (u16*)(ws + o_arena + 20480000);
    u16* qbuf  = (u16*)(ws + o_arena + 40960000);
    u16* kvbuf = (u16*)(ws + o_arena + 46080000);
    u16* aobuf = (u16*)(ws + o_arena + 87040000);
    u16* xw    = (u16*)(ws + o_arena);                    // bf16 [N,256] (phase B)
    u16* qkvh  = (u16*)(ws + o_arena);                    // [N,768] bf16 (phase C)
    float* xacc = (float*)(ws + o_arena + 61440000);      // f32 [N,256]

    const int zero_words = (3 * N_C * 4 + 256) / 4;
    zero_kernel<<<dim3((zero_words + 255) / 256), 256, 0, stream>>>((unsigned int*)cnt, zero_words);

    detect_kernel<<<dim3((E_C / 4 + 255) / 256), 256, 0, stream>>>((const unsigned int*)keep_raw, E_C / 4, flag);
    conv_masks_kernel<<<dim3((E_C + N_C + 255) / 256), 256, 0, stream>>>(keep_raw, nmask_raw, kmask, nmaskb, E_C, N_C, flag);

    // ---- prep: convert embeddings, transpose weights, fuse biases ----
    conv3_kernel<<<dim3(2048), 256, 0, stream>>>(user_emb, NU_C * 16, wine_emb, NI_C * 16,
                                                 wsf, N_C * 16, ue16, we16, wsf16);
    wtrans_kernel<<<dim3(WT_ELEMS / 256), 256, 0, stream>>>(up_w, wp_w, sf_proj_w, sf_q_w,
        sf_k_w, sf_v_w, sf_o_w, sf_fc_w, g_w, t_skip_w, t_q_w, t_k_w, t_v_w, WT);
    prep_bias_kernel<<<dim3(12), 256, 0, stream>>>(sf_k_b, sf_v_b, t_q_b, t_k_b, t_v_b, kvb, qkvb);

    // ---- phase A ----
    mgemm_kernel<u16><<<dim3(2, 118), 512, 0, stream>>>(ue16, 64, wt_up, up_b, xb, 256, NU_C, 256, 64);
    mgemm_kernel<u16><<<dim3(2, 40), 512, 0, stream>>>(we16, 64, wt_wp, wp_b, cat, 512, NI_C, 256, 64);
    mgemm_kernel<u16><<<dim3(2, 157), 512, 0, stream>>>(wsf16, 64, wt_proj, sf_proj_b, side, 256, N_C, 256, 64);
    mgemm_kernel<u16><<<dim3(2, 40), 512, 0, stream>>>(cat, 512, wt_sfq, sf_q_b, qbuf, 256, NI_C, 256, 256);
    mgemm_kernel<u16><<<dim3(4, 157), 512, 0, stream>>>(side, 256, wt_sfkv, kvb, kvbuf, 512, N_C, 512, 256);
    side_attn_kernel<<<dim3(2500), 256, 0, stream>>>(qbuf, kvbuf, aobuf, NI_C);
    mgemm_kernel<u16><<<dim3(2, 40), 512, 0, stream>>>(aobuf, 256, wt_sfo, sf_o_b, cat + 256, 512, NI_C, 256, 256);
    mgemm_kernel<u16><<<dim3(2, 40), 512, 0, stream>>>(cat, 512, wt_sffc, sf_fc_b, xb + (size_t)NU_C * 256, 256, NI_C, 256, 512);

    // ---- deterministic CSR (count+degw fused; atomic fill + per-node sort; edge flatten) ----
    count_kernel<<<dim3((E_C + 255) / 256), 256, 0, stream>>>(e_dst, kmask, cnt, degw, E_C);
    dinv_kernel<<<dim3((N_C + 255) / 256), 256, 0, stream>>>(degw, dinvb, N_C);
    scan_kernel<<<dim3(1), 1024, 0, stream>>>(cnt, rowst, N_C);
    fill_kernel<<<dim3((E_C + 255) / 256), 256, 0, stream>>>(e_dst, rowst, cursor, eid, E_C);
    sort_kernel<<<dim3((N_C + 255) / 256), 256, 0, stream>>>(rowst, eid, N_C);
    edge_prep_kernel<<<dim3((E_C + 255) / 256), 256, 0, stream>>>(eid, e_src, e_dst, kmask, dinvb, ssrc, wnorm, E_C);

    // ---- phase B: GCN ----
    mgemm_kernel<u16><<<dim3(2, 157), 512, 0, stream>>>(xb, 256, wt_g, nullptr, xw, 256, N_C, 256, 256);
    gcn_kernel<<<dim3(N_C / 4), 256, 0, stream>>>(xw, ssrc, wnorm, rowst, dinvb, g_b, xb, N_C);

    // ---- phase C: skip + per-head fused QKV + tconv ----
    mgemm_kernel<float><<<dim3(2, 157), 512, 0, stream>>>(xb, 256, wt_skip, t_skip_b, xacc, 256, N_C, 256, 256);
    for (int h = 0; h < 4; ++h) {
        mgemm_kernel<u16><<<dim3(6, 157), 512, 0, stream>>>(xb, 256, wt_qkv + h * 196608,
                                                            qkvb + h * 768, qkvh, 768, N_C, 768, 256);
        tconv_head_kernel<<<dim3(N_C / 4), 256, 0, stream>>>(qkvh, ssrc, rowst, xacc, N_C);
    }

    // ---- losses + scores ----
    recon_kernel<<<dim3(2048), 256, 0, stream>>>(xacc, nmaskb, ae_b, rblkS, rblkC, N_C);
    score_kernel<<<dim3(2048), 256, 0, stream>>>(xacc, user, wine, ep_w, ep_b, fc_w, fc_b, out, sblk, B_C);
    final_reduce_kernel<<<dim3(1), 1024, 0, stream>>>(rblkS, rblkC, sblk, out, B_C);
}